// Round 11
// baseline (335.450 us; speedup 1.0000x reference)
//
#include <hip/hip_runtime.h>
#include <hip/hip_bf16.h>
#include <cstddef>
#include <cstdint>

// ---------------- problem constants ----------------
#define MROWS 2048           // B8*L256
#define KBIG  16384          // DIN*CH32

typedef __attribute__((ext_vector_type(8))) short short8v;
typedef __attribute__((ext_vector_type(4))) float f32x4;
typedef unsigned int u32;

// ---------------- ws layout (float offsets) ----------------
static const size_t F_XT0  = 0;          // 2048*256
static const size_t F_SKIP = 524288;     // 2048*256
static const size_t F_XS   = 1048576;    // 2048*256
static const size_t F_XZ   = 1572864;    // 2048*1024
static const size_t F_XC   = 3670016;    // 2048*512
static const size_t F_XDBL = 4718592;    // 2048*64 (BC only)
static const size_t F_DT   = 4882432;    // 2048*512
static const size_t F_YG   = 5931008;    // 2048*512
static const size_t F_XS2  = 7503872;    // 2048*256
static const size_t F_DEC  = 9076736;    // 2048*256 (ends 9601024)
static const size_t F_WMED = 9700000;    // med W tiles + conv W tiles
static const size_t F_WT0  = 10485760;   // lin0 split-bf16 tiles (ends 14680064)
static const size_t F_PART = 14680064;   // lin0 partial slabs 0-15 (ends 23068672)
// lin0 partial slabs 16-31 live at float offset 0 (early chain region, free during lin0).
static const size_t F_WDT  = 23068672;   // dtbc tiles (327680 sh x2) + W2 tiles (131072 sh x2)
static const size_t F_C1   = 10485760;   // conv ping-pong (aliases WT0+PART, dead by then)
static const size_t F_C2   = 0;
static const size_t F_C3   = 14680064;

__device__ __forceinline__ float siluf(float v)     { return v / (1.f + __expf(-v)); }
__device__ __forceinline__ float softplusf(float v) { return v > 20.f ? v : log1pf(__expf(v)); }

__device__ __forceinline__ void split2(float v, short& h, short& l) {
  __hip_bfloat16 hb = __float2bfloat16(v);
  float hf = __bfloat162float(hb);
  __hip_bfloat16 lb = __float2bfloat16(v - hf);
  h = *(short*)&hb; l = *(short*)&lb;
}

__device__ __forceinline__ void glds16(const void* g, void* l) {
  __builtin_amdgcn_global_load_lds((const __attribute__((address_space(1))) u32*)g,
                                   (__attribute__((address_space(3))) u32*)l, 16, 0, 0);
}

#define MFMA3(acc, ah, al, bh, bl)                                            \
  acc = __builtin_amdgcn_mfma_f32_16x16x32_bf16(ah, bh, acc, 0, 0, 0);        \
  acc = __builtin_amdgcn_mfma_f32_16x16x32_bf16(al, bh, acc, 0, 0, 0);        \
  acc = __builtin_amdgcn_mfma_f32_16x16x32_bf16(ah, bl, acc, 0, 0, 0);

// ---------------- device helpers for weight tiling ----------------
__device__ __forceinline__ void med_tile_blk(const float* w, unsigned short* th,
                                             unsigned short* tl, int K, int nslots, int b) {
  int slot = b * 256 + threadIdx.x;
  if (slot >= nslots) return;
  int NS = K >> 5;
  int col = slot & 127, kg = (slot >> 7) & 3, rest = slot >> 9;
  int s = rest % NS, nt = rest / NS;
  const float* src = w + (size_t)(nt * 128 + col) * K + (s << 5) + (kg << 3);
  short8v h8, l8;
#pragma unroll
  for (int j = 0; j < 8; ++j) {
    short hh, ll; split2(src[j], hh, ll);
    h8[j] = hh; l8[j] = ll;
  }
  *(short8v*)(th + (size_t)slot * 8) = h8;
  *(short8v*)(tl + (size_t)slot * 8) = l8;
}

__device__ __forceinline__ void conv_tile_blk(const float* w, unsigned short* th,
                                              unsigned short* tl, int b) {
  int slot = b * 256 + threadIdx.x;   // 320 slots
  if (slot >= 320) return;
  int oc = slot & 15;
  int sfq = slot >> 4;
  int s = sfq >> 2, fq = sfq & 3;
  short8v h8, l8;
#pragma unroll
  for (int j = 0; j < 8; ++j) {
    int k = s * 32 + fq * 8 + j;
    float v = 0.f;
    if (k < 144) {
      int dydx = k >> 4, ic = k & 15;
      v = w[oc * 144 + ic * 9 + dydx];
    }
    short hh, ll; split2(v, hh, ll);
    h8[j] = hh; l8[j] = ll;
  }
  *(short8v*)(th + (size_t)slot * 8) = h8;
  *(short8v*)(tl + (size_t)slot * 8) = l8;
}

// dtbc fused weight: N=640, K=512. rows 0-511: W'=dt_w@xproj[:16]; 512-575: xproj[16:80]; else 0
__device__ __forceinline__ void wdtbc_tile_blk(const float* dtw, const float* xpw,
                                               unsigned short* th, unsigned short* tl, int b) {
  int slot = b * 256 + threadIdx.x;   // 40960 slots (160 blocks)
  int col = slot & 127, kg = (slot >> 7) & 3, rest = slot >> 9;
  int s = rest & 15, nt = rest >> 4;  // NS = 16
  int d = nt * 128 + col;
  short8v h8, l8;
  if (d < 512) {
    float wrow[16];
#pragma unroll
    for (int r = 0; r < 16; ++r) wrow[r] = dtw[d * 16 + r];
#pragma unroll
    for (int j = 0; j < 8; ++j) {
      int k = s * 32 + kg * 8 + j;
      float v = 0.f;
#pragma unroll
      for (int r = 0; r < 16; ++r) v = fmaf(wrow[r], xpw[r * 512 + k], v);
      short hh, ll; split2(v, hh, ll);
      h8[j] = hh; l8[j] = ll;
    }
  } else {
#pragma unroll
    for (int j = 0; j < 8; ++j) {
      int k = s * 32 + kg * 8 + j;
      float v = (d < 576) ? xpw[(size_t)(d - 512 + 16) * 512 + k] : 0.f;
      short hh, ll; split2(v, hh, ll);
      h8[j] = hh; l8[j] = ll;
    }
  }
  *(short8v*)(th + (size_t)slot * 8) = h8;
  *(short8v*)(tl + (size_t)slot * 8) = l8;
}

// ---------------- mega weight-tiling kernel ----------------
__global__ __launch_bounds__(256) void tile_all(const float* __restrict__ lin0_w,
                                                unsigned short* __restrict__ wt0h,
                                                unsigned short* __restrict__ wt0l,
                                                unsigned short* __restrict__ wmed,
                                                const float* __restrict__ m_in_w,
                                                const float* __restrict__ lin1_w,
                                                const float* __restrict__ m_out_w,
                                                const float* __restrict__ blk_w,
                                                const float* __restrict__ dec_w,
                                                const float* __restrict__ c2_w,
                                                const float* __restrict__ c3_w,
                                                const float* __restrict__ m_dt_w,
                                                const float* __restrict__ m_xproj_w,
                                                unsigned short* __restrict__ wdth,
                                                unsigned short* __restrict__ wdtl,
                                                unsigned short* __restrict__ w2h,
                                                unsigned short* __restrict__ w2l) {
  __shared__ float ls[32 * 264];   // 8448 floats, reused by lin0-transpose and W2 branches
  int b = blockIdx.x;
  int tid = threadIdx.x;
  if (b < 512) {
    int ct = b >> 6, kt = b & 63;
    int c0 = ct << 5, k0 = kt << 8;
    for (int u = tid; u < 2048; u += 256) {
      int col_l = u >> 6, f4i = u & 63;
      int k_l = f4i << 2;
      float4 v = *(const float4*)(lin0_w + (size_t)(c0 + col_l) * KBIG + k0 + k_l);
      float vv[4] = {v.x, v.y, v.z, v.w};
#pragma unroll
      for (int j = 0; j < 4; ++j) {
        int idx = k_l + j;
        ls[col_l * 264 + idx + (idx >> 5)] = vv[j];
      }
    }
    __syncthreads();
    for (int oi = tid; oi < 1024; oi += 256) {
      int col_l = oi & 31, c = oi >> 5;
      short8v h8, l8;
#pragma unroll
      for (int j = 0; j < 8; ++j) {
        float v = ls[col_l * 264 + j * 33 + c];
        short hh, ll; split2(v, hh, ll);
        h8[j] = hh; l8[j] = ll;
      }
      size_t slot = ((size_t)(c * 64 + kt)) * 256 + c0 + col_l;
      *(short8v*)(wt0h + slot * 8) = h8;
      *(short8v*)(wt0l + slot * 8) = l8;
    }
    return;
  }
  b -= 512;
  if (b < 128) { med_tile_blk(m_in_w,  wmed,           wmed + 262144,  256, 32768, b); return; }
  b -= 128;
  if (b < 32)  { med_tile_blk(lin1_w,  wmed + 524288,  wmed + 589824,  256, 8192,  b); return; }
  b -= 32;
  if (b < 64)  { med_tile_blk(dec_w,   wmed + 1048576, wmed + 1179648, 512, 16384, b); return; }
  b -= 64;
  if (b < 2)   { conv_tile_blk(c2_w, wmed + 1310720, wmed + 1313280, b); return; }
  b -= 2;
  if (b < 2)   { conv_tile_blk(c3_w, wmed + 1315840, wmed + 1318400, b); return; }
  b -= 2;
  if (b < 160) { wdtbc_tile_blk(m_dt_w, m_xproj_w, wdth, wdtl, b); return; }
  b -= 160;
  // ---- W2 = blk_w @ m_out_w [256][512], LDS-tiled (64 blocks) ----
  // Block covers 128 d x 16 k (fixed nt, s). Same r-summation order as a plain
  // 0..255 loop -> bit-identical to the previous scattered version.
  {
    int slot = b * 256 + tid;
    int col = slot & 127, kg = (slot >> 7) & 3, rest = slot >> 9;
    int s = rest & 15, nt = rest >> 4;  // NS = 16
    int kb2 = s * 32 + ((b & 1) << 4);  // block's 16-k window base
    float acc[8];
#pragma unroll
    for (int j = 0; j < 8; ++j) acc[j] = 0.f;
    float* ows = ls + 4224;             // [32][16]
    for (int r0 = 0; r0 < 256; r0 += 32) {
      __syncthreads();                  // previous chunk fully consumed
      for (int idx = tid; idx < 4096; idx += 256) {
        int dl = idx >> 5, rr = idx & 31;
        ls[dl * 33 + rr] = blk_w[(size_t)(nt * 128 + dl) * 256 + r0 + rr];
      }
      for (int idx = tid; idx < 512; idx += 256) {
        int rr = idx >> 4, kk = idx & 15;
        ows[rr * 16 + kk] = m_out_w[(size_t)(r0 + rr) * 512 + kb2 + kk];
      }
      __syncthreads();
#pragma unroll 4
      for (int rr = 0; rr < 32; ++rr) {
        float bv = ls[col * 33 + rr];
        const float* op = &ows[rr * 16 + ((kg & 1) << 3)];
#pragma unroll
        for (int j = 0; j < 8; ++j) acc[j] = fmaf(bv, op[j], acc[j]);
      }
    }
    short8v h8, l8;
#pragma unroll
    for (int j = 0; j < 8; ++j) {
      short hh, ll; split2(acc[j], hh, ll);
      h8[j] = hh; l8[j] = ll;
    }
    *(short8v*)(w2h + (size_t)slot * 8) = h8;
    *(short8v*)(w2l + (size_t)slot * 8) = l8;
  }
}

// ---------------- lin0 MFMA GEMM: BM=256, BN=256(full), BK=32, split-K=32 ----------------
__global__ __launch_bounds__(512, 2) void lin0_mfma(const float* __restrict__ x,
                                                    const unsigned short* __restrict__ wh,
                                                    const unsigned short* __restrict__ wl,
                                                    float* __restrict__ wsbase) {
  __shared__ short8v Ad[2][2][1024];
  __shared__ short8v Bd[2][2][1024];
  int bid = blockIdx.x;
  int mt = bid >> 5, z = bid & 31;
  int tid = threadIdx.x;
  int lane = tid & 63, wid = tid >> 6;
  int wm = wid >> 2, wn = wid & 3;
  int fi = lane & 15, fq = lane >> 4;
  int arow = tid >> 1, kh = tid & 1;
  const float* xrow = x + (size_t)mt * 4194304 + (size_t)z * 131072 + (size_t)arow * 512;
  int skg = wid & 3, shl = wid >> 2;
  const unsigned short* wsrc = shl ? wl : wh;
  int aoff[8], boff[4];
#pragma unroll
  for (int mi = 0; mi < 8; ++mi) {
    int row = wm * 128 + mi * 16 + fi;
    aoff[mi] = fq * 256 + (row ^ (fq << 2));
  }
#pragma unroll
  for (int ni = 0; ni < 4; ++ni) boff[ni] = fq * 256 + wn * 64 + ni * 16 + fi;

  f32x4 acc[8][4];
#pragma unroll
  for (int mi = 0; mi < 8; ++mi)
#pragma unroll
    for (int ni = 0; ni < 4; ++ni) acc[mi][ni] = (f32x4)(0.f);

  {
    int slotbase = ((z * 16 + 0) * 4 + skg) * 256;
#pragma unroll
    for (int q = 0; q < 4; ++q)
      glds16(wsrc + (size_t)(slotbase + q * 64 + lane) * 8,
             (void*)&Bd[0][shl][skg * 256 + q * 64]);
    int f0 = kh << 4;
    float vv[16];
#pragma unroll
    for (int j4 = 0; j4 < 4; ++j4) {
      float4 v = *(const float4*)(xrow + f0 + 4 * j4);
      vv[4 * j4] = v.x; vv[4 * j4 + 1] = v.y; vv[4 * j4 + 2] = v.z; vv[4 * j4 + 3] = v.w;
    }
#pragma unroll
    for (int jg = 0; jg < 2; ++jg) {
      short8v h8, l8;
#pragma unroll
      for (int j = 0; j < 8; ++j) { short hh, ll; split2(vv[jg * 8 + j], hh, ll); h8[j] = hh; l8[j] = ll; }
      int kg = (kh << 1) + jg;
      int idx = kg * 256 + (arow ^ (kg << 2));
      Ad[0][0][idx] = h8; Ad[0][1][idx] = l8;
    }
    __syncthreads();
  }

  for (int s = 0; s < 16; ++s) {
    int cb = s & 1, nb = cb ^ 1;
    bool more = s < 15;
    float vv[16];
    if (more) {
      int slotbase = ((z * 16 + s + 1) * 4 + skg) * 256;
#pragma unroll
      for (int q = 0; q < 4; ++q)
        glds16(wsrc + (size_t)(slotbase + q * 64 + lane) * 8,
               (void*)&Bd[nb][shl][skg * 256 + q * 64]);
      int f0 = ((s + 1) << 5) + (kh << 4);
#pragma unroll
      for (int j4 = 0; j4 < 4; ++j4) {
        float4 v = *(const float4*)(xrow + f0 + 4 * j4);
        vv[4 * j4] = v.x; vv[4 * j4 + 1] = v.y; vv[4 * j4 + 2] = v.z; vv[4 * j4 + 3] = v.w;
      }
    }
    short8v fah[8], fal[8];
#pragma unroll
    for (int mi = 0; mi < 8; ++mi) { fah[mi] = Ad[cb][0][aoff[mi]]; fal[mi] = Ad[cb][1][aoff[mi]]; }
#pragma unroll
    for (int ni = 0; ni < 4; ++ni) {
      short8v bh = Bd[cb][0][boff[ni]];
      short8v bl = Bd[cb][1][boff[ni]];
#pragma unroll
      for (int mi = 0; mi < 8; ++mi) { MFMA3(acc[mi][ni], fah[mi], fal[mi], bh, bl); }
    }
    if (more) {
#pragma unroll
      for (int jg = 0; jg < 2; ++jg) {
        short8v h8, l8;
#pragma unroll
        for (int j = 0; j < 8; ++j) { short hh, ll; split2(vv[jg * 8 + j], hh, ll); h8[j] = hh; l8[j] = ll; }
        int kg = (kh << 1) + jg;
        int idx = kg * 256 + (arow ^ (kg << 2));
        Ad[nb][0][idx] = h8; Ad[nb][1][idx] = l8;
      }
    }
    __syncthreads();
  }

  size_t slabbase = (z < 16) ? (F_PART + (size_t)z * 524288) : ((size_t)(z - 16) * 524288);
  float* po = wsbase + slabbase + (size_t)mt * 65536;
#pragma unroll
  for (int mi = 0; mi < 8; ++mi)
#pragma unroll
    for (int ni = 0; ni < 4; ++ni) {
      int mloc = wm * 128 + mi * 16 + fq * 4;
      int n = wn * 64 + ni * 16 + fi;
#pragma unroll
      for (int r = 0; r < 4; ++r)
        po[(size_t)(mloc + r) * 256 + n] = acc[mi][ni][r];
    }
}

// ---------------- medium MFMA GEMM: BM=64, BN=128, BK=32, A+B dbuf (1 barrier/step) ----------------
template <int ACT, int HASBIAS, int SRC2, int DTBC>
__global__ __launch_bounds__(256, 2) void med_mfma(const float* __restrict__ A, int lda,
                                                   const float* __restrict__ A2,
                                                   const unsigned short* __restrict__ wh,
                                                   const unsigned short* __restrict__ wl,
                                                   const float* __restrict__ bias,
                                                   float* __restrict__ out,
                                                   float* __restrict__ bc_out,
                                                   int K, int N) {
  __shared__ short8v Ahs[2][2][256];
  __shared__ short8v Bd[2][2][512];
  int nt = blockIdx.x, mt = blockIdx.y;
  int NS = K >> 5;
  int tid = threadIdx.x;
  int lane = tid & 63, wid = tid >> 6;
  int fi = lane & 15, fq = lane >> 4;
  int arow = tid >> 2, akg = tid & 3;
  int awidx = akg * 64 + (arow ^ (akg << 2));
  int m0 = mt << 6;
  size_t wtbase = (size_t)nt * NS;
  int aoff[4], boff[2];
#pragma unroll
  for (int mi = 0; mi < 4; ++mi) {
    int row = mi * 16 + fi;
    aoff[mi] = fq * 64 + (row ^ (fq << 2));
  }
#pragma unroll
  for (int ni = 0; ni < 2; ++ni) boff[ni] = fq * 128 + wid * 32 + ni * 16 + fi;

  f32x4 acc[4][2];
#pragma unroll
  for (int mi = 0; mi < 4; ++mi)
#pragma unroll
    for (int ni = 0; ni < 2; ++ni) acc[mi][ni] = (f32x4)(0.f);

  {
#pragma unroll
    for (int p = 0; p < 2; ++p) {
      int q = (wid << 1) + p;
      size_t gb = wtbase * 8192 + (size_t)q * 1024 + (size_t)lane * 16;
      glds16((const char*)wh + gb, (char*)&Bd[0][0][0] + q * 1024);
      glds16((const char*)wl + gb, (char*)&Bd[0][1][0] + q * 1024);
    }
    const float* gp = A + (size_t)(m0 + arow) * lda + (akg << 3);
    float4 v0 = *(const float4*)gp, v1 = *(const float4*)(gp + 4);
    float vv[8] = {v0.x, v0.y, v0.z, v0.w, v1.x, v1.y, v1.z, v1.w};
    short8v h8, l8;
#pragma unroll
    for (int j = 0; j < 8; ++j) { short hh, ll; split2(vv[j], hh, ll); h8[j] = hh; l8[j] = ll; }
    Ahs[0][0][awidx] = h8; Ahs[0][1][awidx] = l8;
    __syncthreads();
  }

  for (int s = 0; s < NS; ++s) {
    int cb = s & 1, nb = cb ^ 1;
    bool more = (s + 1) < NS;
    float4 v0, v1;
    if (more) {
#pragma unroll
      for (int p = 0; p < 2; ++p) {
        int q = (wid << 1) + p;
        size_t gb = (wtbase + s + 1) * 8192 + (size_t)q * 1024 + (size_t)lane * 16;
        glds16((const char*)wh + gb, (char*)&Bd[nb][0][0] + q * 1024);
        glds16((const char*)wl + gb, (char*)&Bd[nb][1][0] + q * 1024);
      }
      int sk = (s + 1) << 5;
      const float* gp;
      if (SRC2 && sk >= 256)
        gp = A2 + (size_t)(m0 + arow) * 256 + (sk - 256) + (akg << 3);
      else
        gp = A + (size_t)(m0 + arow) * lda + sk + (akg << 3);
      v0 = *(const float4*)gp; v1 = *(const float4*)(gp + 4);
    }
    short8v fah[4], fal[4];
#pragma unroll
    for (int mi = 0; mi < 4; ++mi) { fah[mi] = Ahs[cb][0][aoff[mi]]; fal[mi] = Ahs[cb][1][aoff[mi]]; }
#pragma unroll
    for (int ni = 0; ni < 2; ++ni) {
      short8v bh = Bd[cb][0][boff[ni]];
      short8v bl = Bd[cb][1][boff[ni]];
#pragma unroll
      for (int mi = 0; mi < 4; ++mi) { MFMA3(acc[mi][ni], fah[mi], fal[mi], bh, bl); }
    }
    if (more) {
      float vv[8] = {v0.x, v0.y, v0.z, v0.w, v1.x, v1.y, v1.z, v1.w};
      short8v h8, l8;
#pragma unroll
      for (int j = 0; j < 8; ++j) { short hh, ll; split2(vv[j], hh, ll); h8[j] = hh; l8[j] = ll; }
      Ahs[nb][0][awidx] = h8; Ahs[nb][1][awidx] = l8;
    }
    __syncthreads();
  }

#pragma unroll
  for (int mi = 0; mi < 4; ++mi)
#pragma unroll
    for (int ni = 0; ni < 2; ++ni) {
      int n = (nt << 7) + wid * 32 + ni * 16 + fi;
#pragma unroll
      for (int r = 0; r < 4; ++r) {
        int m = m0 + mi * 16 + fq * 4 + r;
        float a = acc[mi][ni][r];
        if (DTBC) {
          if (n < 512) out[(size_t)m * 512 + n] = softplusf(a + bias[n]);
          else if (n < 576) bc_out[(size_t)m * 64 + (n - 512)] = a;
        } else {
          float v = a + (HASBIAS ? bias[n] : 0.f);
          if (ACT == 1) v = fmaxf(v, 0.f);
          out[(size_t)m * N + n] = v;
        }
      }
    }
}

// ---------------- sum 32 partials + bias -> relu -> LayerNorm ----------------
__global__ __launch_bounds__(256) void ln32_k(const float* part_a, const float* part_b,
                                              const float* __restrict__ bias,
                                              const float* __restrict__ g,
                                              const float* __restrict__ bb,
                                              float* out) {
  int m = blockIdx.x, t = threadIdx.x;
  float s = bias[t];
  for (int z = 0; z < 16; ++z) s += part_a[((size_t)z * MROWS + m) * 256 + t];
  for (int z = 0; z < 16; ++z) s += part_b[((size_t)z * MROWS + m) * 256 + t];
  float v = fmaxf(s, 0.f);
  float sum = v, sq = v * v;
#pragma unroll
  for (int o = 1; o < 64; o <<= 1) { sum += __shfl_xor(sum, o); sq += __shfl_xor(sq, o); }
  __shared__ float s1[4], s2[4];
  int w = t >> 6;
  if ((t & 63) == 0) { s1[w] = sum; s2[w] = sq; }
  __syncthreads();
  sum = s1[0] + s1[1] + s1[2] + s1[3];
  sq  = s2[0] + s2[1] + s2[2] + s2[3];
  float mu  = sum * (1.f / 256.f);
  float var = sq * (1.f / 256.f) - mu * mu;
  out[(size_t)m * 256 + t] = (v - mu) * rsqrtf(var + 1e-5f) * g[t] + bb[t];
}

// ---------------- 1 partial + bias -> relu -> LN -> skip AND xs=skip+pos ----------------
__global__ __launch_bounds__(256) void ln_pos_k(const float* __restrict__ part,
                                                const float* __restrict__ bias,
                                                const float* __restrict__ g,
                                                const float* __restrict__ bb,
                                                const float* __restrict__ pos,
                                                float* __restrict__ skip,
                                                float* __restrict__ xs) {
  int m = blockIdx.x, t = threadIdx.x;
  float s = bias[t] + part[(size_t)m * 256 + t];
  float v = fmaxf(s, 0.f);
  float sum = v, sq = v * v;
#pragma unroll
  for (int o = 1; o < 64; o <<= 1) { sum += __shfl_xor(sum, o); sq += __shfl_xor(sq, o); }
  __shared__ float s1[4], s2[4];
  int w = t >> 6;
  if ((t & 63) == 0) { s1[w] = sum; s2[w] = sq; }
  __syncthreads();
  sum = s1[0] + s1[1] + s1[2] + s1[3];
  sq  = s2[0] + s2[1] + s2[2] + s2[3];
  float mu  = sum * (1.f / 256.f);
  float var = sq * (1.f / 256.f) - mu * mu;
  float o2 = (v - mu) * rsqrtf(var + 1e-5f) * g[t] + bb[t];
  skip[(size_t)m * 256 + t] = o2;
  xs[(size_t)m * 256 + t] = o2 + pos[(m & 255) * 256 + t];
}

// ---------------- causal depthwise conv1d(k=4) + silu ----------------
__global__ __launch_bounds__(256) void conv1d_silu_k(const float* __restrict__ xz,
                                                     const float* __restrict__ w,
                                                     const float* __restrict__ cb,
                                                     float* __restrict__ xc) {
  int i = blockIdx.x * 256 + threadIdx.x;  // over 2048*512
  int m = i >> 9, d = i & 511;
  int b = m >> 8, l = m & 255;
  float s = cb[d];
#pragma unroll
  for (int j = 0; j < 4; ++j) {
    int ll = l - 3 + j;
    if (ll >= 0) s = fmaf(w[(d << 2) + j], xz[((size_t)((b << 8) + ll) << 10) + d], s);
  }
  xc[(size_t)m * 512 + d] = siluf(s);
}

// ---------------- selective scan (16-step windows, dbuf pbuf -> 1 barrier/window) ----------------
__global__ __launch_bounds__(256, 1) void scan_k(const float* __restrict__ dt,
                                                 const float* __restrict__ u,
                                                 const float* __restrict__ bc,
                                                 const float* __restrict__ Alog,
                                                 const float* __restrict__ Dp,
                                                 const float* __restrict__ xz,
                                                 float* __restrict__ yg) {
  __shared__ float pbuf[2][4][2][16][33];
  int tid  = threadIdx.x;
  int widx = tid >> 6, lane = tid & 63;
  int wid  = (blockIdx.x << 2) + widx;
  int n = lane & 31, ch = lane >> 5;
  int d0 = (wid & 255) << 1;
  int d = d0 + ch;
  int b = wid >> 8;
  size_t base = (size_t)b << 8;
  float Av = -__expf(Alog[(d << 5) + n]);
  float Dv0 = Dp[d0], Dv1 = Dp[d0 + 1];
  float h = 0.f;
  int row = lane & 31;
  int rch = row >> 4, rlp = row & 15;
  int nh  = lane >> 5;
  int drow = d0 + rch;
  float Dsel = rch ? Dv1 : Dv0;

  for (int w0 = 0; w0 < 256; w0 += 16) {
    int wb = (w0 >> 4) & 1;
    float dA[16], dBu[16], Cv[16];
#pragma unroll
    for (int j = 0; j < 16; ++j) {
      size_t r = base + w0 + j;
      float dtv = dt[(r << 9) + d];
      float uv  = u [(r << 9) + d];
      float Bv  = bc[(r << 6) + n];
      Cv[j]     = bc[(r << 6) + 32 + n];
      dA[j]  = __expf(dtv * Av);
      dBu[j] = dtv * Bv * uv;
    }
#pragma unroll
    for (int j = 0; j < 16; ++j) {
      h = fmaf(dA[j], h, dBu[j]);
      pbuf[wb][widx][ch][j][n] = h * Cv[j];
    }
    __syncthreads();
    float s = 0.f;
#pragma unroll
    for (int nn = 0; nn < 16; ++nn) s += pbuf[wb][widx][rch][rlp][(nh << 4) + nn];
    s += __shfl_xor(s, 32);
    if (lane < 32) {
      size_t r = base + w0 + rlp;
      float uv = u[(r << 9) + drow];
      float zv = xz[(r << 10) + 512 + drow];
      yg[(r << 9) + drow] = (s + uv * Dsel) * siluf(zv);
    }
    // no trailing barrier: next window writes the other pbuf; reuse of this one
    // is fenced by that window's barrier.
  }
}

// ---------------- direct 3x3 conv (IC=1), relu ----------------
template <int IC>
__global__ __launch_bounds__(256) void conv3x3_k(const float* __restrict__ in,
                                                 const float* __restrict__ w,
                                                 const float* __restrict__ bias,
                                                 float* __restrict__ out) {
  __shared__ float t[IC][6][68];
  __shared__ float wl[IC * 144];
  __shared__ float bl[16];
  int bid = blockIdx.x;
  int x0 = (bid & 3) << 6;
  int y0 = ((bid >> 2) & 63) << 2;
  int bb = bid >> 8;
  int tid = threadIdx.x;
  for (int i = tid; i < IC * 144; i += 256) {
    int oc = i & 15, t2 = i >> 4;
    wl[i] = w[(size_t)oc * (IC * 9) + t2];
  }
  if (tid < 16) bl[tid] = bias[tid];
  for (int i = tid; i < IC * 396; i += 256) {
    int ic = i / 396, rem = i - ic * 396;
    int r = rem / 66, cx = rem - r * 66;
    int y = y0 - 1 + r, xx = x0 - 1 + cx;
    float v = 0.f;
    if (y >= 0 && y < 256 && xx >= 0 && xx < 256)
      v = in[(((size_t)bb * IC + ic) << 16) + (y << 8) + xx];
    t[ic][r][cx] = v;
  }
  __syncthreads();
  int tx = tid & 15, row = (tid >> 4) & 3, ocq = tid >> 6;
  float acc[4][4];
#pragma unroll
  for (int o = 0; o < 4; ++o)
#pragma unroll
    for (int p = 0; p < 4; ++p) acc[o][p] = 0.f;

  for (int ic = 0; ic < IC; ++ic) {
#pragma unroll
    for (int dy = 0; dy < 3; ++dy) {
      const float* rp = &t[ic][row + dy][tx << 2];
      float rv[6];
#pragma unroll
      for (int q = 0; q < 6; ++q) rv[q] = rp[q];
#pragma unroll
      for (int dx = 0; dx < 3; ++dx) {
        const float* wp4 = &wl[(((ic * 3 + dy) * 3 + dx) << 4) + (ocq << 2)];
#pragma unroll
        for (int o = 0; o < 4; ++o) {
          float wv = wp4[o];
#pragma unroll
          for (int p = 0; p < 4; ++p) acc[o][p] = fmaf(rv[p + dx], wv, acc[o][p]);
        }
      }
    }
  }
  int xo = x0 + (tx << 2), yo = y0 + row;
#pragma unroll
  for (int o = 0; o < 4; ++o) {
    int oc = (ocq << 2) + o;
    float4 v4;
    v4.x = fmaxf(acc[o][0] + bl[oc], 0.f);
    v4.y = fmaxf(acc[o][1] + bl[oc], 0.f);
    v4.z = fmaxf(acc[o][2] + bl[oc], 0.f);
    v4.w = fmaxf(acc[o][3] + bl[oc], 0.f);
    *(float4*)&out[(((size_t)bb * 16 + oc) << 16) + (yo << 8) + xo] = v4;
  }
}

// ---------------- MFMA implicit-GEMM 3x3 conv, IC=OC=16, relu ----------------
__global__ __launch_bounds__(256, 2) void conv_mfma(const float* __restrict__ in,
                                                    const unsigned short* __restrict__ wth,
                                                    const unsigned short* __restrict__ wtl,
                                                    const float* __restrict__ bias,
                                                    float* __restrict__ out) {
  __shared__ __align__(16) char smem[58752];
  unsigned short* inh = (unsigned short*)smem;
  unsigned short* inl = inh + 14688;
  int bid = blockIdx.x;
  int txi = bid & 7;
  int tyi = (bid >> 3) & 15;
  int bb  = bid >> 7;
  int x0 = txi << 5, y0 = tyi << 4;
  int tid = threadIdx.x;

  for (int i = tid; i < 9792; i += 256) {
    int ic = i / 612, rem = i - ic * 612;
    int y = rem / 34, xx = rem - y * 34;
    int gy = y0 + y - 1, gx = x0 + xx - 1;
    float v = 0.f;
    if (gy >= 0 && gy < 256 && gx >= 0 && gx < 256)
      v = in[(((size_t)bb * 16 + ic) << 16) + (gy << 8) + gx];
    short hh, ll; split2(v, hh, ll);
    int a = (y * 34 + xx) * 24 + ic;
    inh[a] = (unsigned short)hh; inl[a] = (unsigned short)ll;
  }
  __syncthreads();

  int lane = tid & 63, w = tid >> 6;
  int fi = lane & 15, fq = lane >> 4;
  int fqh = fq >> 1, ich8 = (fq & 1) << 3;

  int adel[5];
#pragma unroll
  for (int s = 0; s < 5; ++s) {
    int dydx = 2 * s + fqh;
    if (dydx > 8) dydx = 8;
    int dy = dydx / 3, dx = dydx - dy * 3;
    adel[s] = (dy * 34 + dx) * 24;
  }
  int abase[8];
#pragma unroll
  for (int q = 0; q < 8; ++q) {
    int px = ((w * 8 + q) << 4) + fi;
    int y = px >> 5, xx = px & 31;
    abase[q] = (y * 34 + xx) * 24 + ich8;
  }
  short8v bh[5], bl[5];
#pragma unroll
  for (int s = 0; s < 5; ++s) {
    int slot = ((s * 4 + fq) * 16 + fi) * 8;
    bh[s] = *(const short8v*)(wth + slot);
    bl[s] = *(const short8v*)(wtl + slot);
  }

  f32x4 acc[8];
#pragma unroll
  for (int q = 0; q < 8; ++q) acc[q] = (f32x4)(0.f);

#pragma unroll
  for (int s = 0; s < 5; ++s) {
#pragma unroll
    for (int q = 0; q < 8; ++q) {
      short8v ah = *(const short8v*)&inh[abase[q] + adel[s]];
      short8v al = *(const short8v*)&inl[abase[q] + adel[s]];
      MFMA3(acc[q], ah, al, bh[s], bl[s]);
    }
  }
  __syncthreads();

  float* outs = (float*)smem;
#pragma unroll
  for (int q = 0; q < 8; ++q) {
    int pxb = ((w * 8 + q) << 4) + (fq << 2);
#pragma unroll
    for (int r = 0; r < 4; ++r)
      outs[fi * 514 + pxb + r] = acc[q][r];
  }
  __syncthreads();
  for (int i = tid; i < 8192; i += 256) {
    int oc = i >> 9, px = i & 511;
    int y = px >> 5, xx = px & 31;
    float v = fmaxf(outs[oc * 514 + px] + bias[oc], 0.f);
    out[(((size_t)bb * 16 + oc) << 16) + ((y0 + y) << 8) + x0 + xx] = v;
  }
}

// ---------------- 2x2 mean pool + 1x1 conv (16->1), coalesced float4 reads ----------------
__global__ __launch_bounds__(256) void pool_c4_k(const float* __restrict__ in,
                                                 const float* __restrict__ w4,
                                                 const float* __restrict__ b4,
                                                 float* __restrict__ out) {
  int i = blockIdx.x * 256 + threadIdx.x;  // 8*128*64 units (2 outputs each)
  int xq = i & 63, y = (i >> 6) & 127, b = i >> 13;
  float s0 = b4[0], s1 = b4[0];
#pragma unroll
  for (int ic = 0; ic < 16; ++ic) {
    const float* p = in + (((size_t)b * 16 + ic) << 16) + ((size_t)(y << 1) << 8) + (xq << 2);
    float4 a0 = *(const float4*)p;
    float4 a1 = *(const float4*)(p + 256);
    float m0 = 0.25f * (a0.x + a0.y + a1.x + a1.y);
    float m1 = 0.25f * (a0.z + a0.w + a1.z + a1.w);
    float wv = w4[ic];
    s0 = fmaf(wv, m0, s0);
    s1 = fmaf(wv, m1, s1);
  }
  float2 o2 = make_float2(s0, s1);
  *(float2*)&out[(size_t)b * 16384 + y * 128 + (xq << 1)] = o2;
}

// ---------------- launcher ----------------
extern "C" void kernel_launch(void* const* d_in, const int* in_sizes, int n_in,
                              void* d_out, int out_size, void* d_ws, size_t ws_size,
                              hipStream_t stream) {
  const float* x        = (const float*)d_in[0];
  const float* lin0_w   = (const float*)d_in[1];
  const float* lin0_b   = (const float*)d_in[2];
  const float* ln0_g    = (const float*)d_in[3];
  const float* ln0_bb   = (const float*)d_in[4];
  const float* lin1_w   = (const float*)d_in[5];
  const float* lin1_b   = (const float*)d_in[6];
  const float* ln1_g    = (const float*)d_in[7];
  const float* ln1_bb   = (const float*)d_in[8];
  const float* pos      = (const float*)d_in[9];
  const float* m_in_w   = (const float*)d_in[10];
  const float* m_conv_w = (const float*)d_in[11];
  const float* m_conv_b = (const float*)d_in[12];
  const float* m_xproj_w= (const float*)d_in[13];
  const float* m_dt_w   = (const float*)d_in[14];
  const float* m_dt_b   = (const float*)d_in[15];
  const float* m_Alog   = (const float*)d_in[16];
  const float* m_D      = (const float*)d_in[17];
  const float* m_out_w  = (const float*)d_in[18];
  const float* blk_w    = (const float*)d_in[19];
  const float* blk_b    = (const float*)d_in[20];
  const float* dec_w    = (const float*)d_in[21];
  const float* dec_b    = (const float*)d_in[22];
  const float* c1_w     = (const float*)d_in[23];
  const float* c1_b     = (const float*)d_in[24];
  const float* c2_w     = (const float*)d_in[25];
  const float* c2_b     = (const float*)d_in[26];
  const float* c3_w     = (const float*)d_in[27];
  const float* c3_b     = (const float*)d_in[28];
  const float* c4_w     = (const float*)d_in[29];
  const float* c4_b     = (const float*)d_in[30];

  float* ws  = (float*)d_ws;
  float* out = (float*)d_out;

  unsigned short* wt0h = (unsigned short*)(ws + F_WT0);
  unsigned short* wt0l = wt0h + 4194304;
  unsigned short* wmed = (unsigned short*)(ws + F_WMED);
  unsigned short* inw_h = wmed,           * inw_l = wmed + 262144;
  unsigned short* l1_h  = wmed + 524288,  * l1_l  = wmed + 589824;
  unsigned short* dc_h  = wmed + 1048576, * dc_l  = wmed + 1179648;
  unsigned short* wc2h  = wmed + 1310720, * wc2l  = wmed + 1313280;
  unsigned short* wc3h  = wmed + 1315840, * wc3l  = wmed + 1318400;
  unsigned short* wdth  = (unsigned short*)(ws + F_WDT);
  unsigned short* wdtl  = wdth + 327680;
  unsigned short* w2h   = wdtl + 327680;
  unsigned short* w2l   = w2h + 131072;

  // 1. ALL weight tiling in one launch (964 blocks)
  tile_all<<<964, 256, 0, stream>>>(lin0_w, wt0h, wt0l, wmed,
                                    m_in_w, lin1_w, m_out_w, blk_w, dec_w,
                                    c2_w, c3_w, m_dt_w, m_xproj_w,
                                    wdth, wdtl, w2h, w2l);
  // 2. lin0 MFMA GEMM -> 32 partial slabs
  lin0_mfma<<<256, 512, 0, stream>>>(x, wt0h, wt0l, ws);
  // 3. reduce 32 + bias + relu + LN0 -> xt0
  ln32_k<<<MROWS, 256, 0, stream>>>(ws + F_PART, ws, lin0_b, ln0_g, ln0_bb, ws + F_XT0);
  // 4. lin1 -> part (raw)
  med_mfma<0, 0, 0, 0><<<dim3(2, 32), 256, 0, stream>>>(ws + F_XT0, 256, nullptr, l1_h, l1_l,
                                                        nullptr, ws + F_PART, nullptr, 256, 256);
  // 5. bias+relu+LN1 -> skip AND xs = skip+pos
  ln_pos_k<<<MROWS, 256, 0, stream>>>(ws + F_PART, lin1_b, ln1_g, ln1_bb, pos,
                                      ws + F_SKIP, ws + F_XS);
  // 6. xz = xs @ m_in_w^T  [2048,1024]
  med_mfma<0, 0, 0, 0><<<dim3(8, 32), 256, 0, stream>>>(ws + F_XS, 256, nullptr, inw_h, inw_l,
                                                        nullptr, ws + F_XZ, nullptr, 256, 1024);
  // 7. causal dwconv + silu -> xc
  conv1d_silu_k<<<4096, 256, 0, stream>>>(ws + F_XZ, m_conv_w, m_conv_b, ws + F_XC);
  // 8. fused dt+BC
  med_mfma<0, 1, 0, 1><<<dim3(5, 32), 256, 0, stream>>>(ws + F_XC, 512, nullptr, wdth, wdtl,
                                                        m_dt_b, ws + F_DT, ws + F_XDBL, 512, 512);
  // 9. selective scan + silu(z) gating -> yg
  scan_k<<<512, 256, 0, stream>>>(ws + F_DT, ws + F_XC, ws + F_XDBL, m_Alog, m_D,
                                  ws + F_XZ, ws + F_YG);
  // 10. xs2 = yg @ W2^T + blk_b
  med_mfma<0, 1, 0, 0><<<dim3(2, 32), 256, 0, stream>>>(ws + F_YG, 512, nullptr, w2h, w2l,
                                                        blk_b, ws + F_XS2, nullptr, 512, 256);
  // 11. dec = relu([xs2|skip] @ dec_w^T + dec_b)
  med_mfma<1, 1, 1, 0><<<dim3(2, 32), 256, 0, stream>>>(ws + F_XS2, 256, ws + F_SKIP, dc_h, dc_l,
                                                        dec_b, ws + F_DEC, nullptr, 512, 256);
  // 12. conv1 (IC=1, scalar)
  conv3x3_k<1><<<2048, 256, 0, stream>>>(ws + F_DEC, c1_w, c1_b, ws + F_C1);
  // 13-14. conv2/conv3 via MFMA implicit GEMM
  conv_mfma<<<1024, 256, 0, stream>>>(ws + F_C1, wc2h, wc2l, c2_b, ws + F_C2);
  conv_mfma<<<1024, 256, 0, stream>>>(ws + F_C2, wc3h, wc3l, c3_b, ws + F_C3);
  // 15. pool + 1x1 conv -> out (coalesced, 2 outputs/thread)
  pool_c4_k<<<256, 256, 0, stream>>>(ws + F_C3, c4_w, c4_b, out);
}

// Round 12
// 304.514 us; speedup vs baseline: 1.1016x; 1.1016x over previous
//
#include <hip/hip_runtime.h>
#include <hip/hip_bf16.h>
#include <cstddef>
#include <cstdint>

// ---------------- problem constants ----------------
#define MROWS 2048           // B8*L256
#define KBIG  16384          // DIN*CH32

typedef __attribute__((ext_vector_type(8))) short short8v;
typedef __attribute__((ext_vector_type(4))) float f32x4;
typedef unsigned int u32;

// ---------------- ws layout (float offsets) ----------------
static const size_t F_XT0  = 0;          // 2048*256
static const size_t F_SKIP = 524288;     // 2048*256
static const size_t F_XS   = 1048576;    // 2048*256
static const size_t F_XZ   = 1572864;    // 2048*1024
static const size_t F_XC   = 3670016;    // 2048*512
static const size_t F_XDBL = 4718592;    // 2048*64 (BC only)
static const size_t F_DT   = 4882432;    // 2048*512
static const size_t F_YG   = 5931008;    // 2048*512
static const size_t F_XS2  = 7503872;    // 2048*256
static const size_t F_DEC  = 9076736;    // 2048*256 (ends 9601024)
static const size_t F_WMED = 9700000;    // med W tiles + conv W tiles
static const size_t F_WT0  = 10485760;   // lin0 split-bf16 tiles (ends 14680064)
static const size_t F_PART = 14680064;   // lin0 partial slabs 0-15 (ends 23068672)
// lin0 partial slabs 16-31 live at float offset 0 (early chain region, free during lin0).
static const size_t F_WDT  = 23068672;   // dtbc tiles + W2 tiles
static const size_t F_C2   = 0;          // conv2 output (aliases early chain; DEC @9076736 safe)

__device__ __forceinline__ float siluf(float v)     { return v / (1.f + __expf(-v)); }
__device__ __forceinline__ float softplusf(float v) { return v > 20.f ? v : log1pf(__expf(v)); }

__device__ __forceinline__ void split2(float v, short& h, short& l) {
  __hip_bfloat16 hb = __float2bfloat16(v);
  float hf = __bfloat162float(hb);
  __hip_bfloat16 lb = __float2bfloat16(v - hf);
  h = *(short*)&hb; l = *(short*)&lb;
}

__device__ __forceinline__ void glds16(const void* g, void* l) {
  __builtin_amdgcn_global_load_lds((const __attribute__((address_space(1))) u32*)g,
                                   (__attribute__((address_space(3))) u32*)l, 16, 0, 0);
}

#define MFMA3(acc, ah, al, bh, bl)                                            \
  acc = __builtin_amdgcn_mfma_f32_16x16x32_bf16(ah, bh, acc, 0, 0, 0);        \
  acc = __builtin_amdgcn_mfma_f32_16x16x32_bf16(al, bh, acc, 0, 0, 0);        \
  acc = __builtin_amdgcn_mfma_f32_16x16x32_bf16(ah, bl, acc, 0, 0, 0);

// ---------------- device helpers for weight tiling ----------------
__device__ __forceinline__ void med_tile_blk(const float* w, unsigned short* th,
                                             unsigned short* tl, int K, int nslots, int b) {
  int slot = b * 256 + threadIdx.x;
  if (slot >= nslots) return;
  int NS = K >> 5;
  int col = slot & 127, kg = (slot >> 7) & 3, rest = slot >> 9;
  int s = rest % NS, nt = rest / NS;
  const float* src = w + (size_t)(nt * 128 + col) * K + (s << 5) + (kg << 3);
  short8v h8, l8;
#pragma unroll
  for (int j = 0; j < 8; ++j) {
    short hh, ll; split2(src[j], hh, ll);
    h8[j] = hh; l8[j] = ll;
  }
  *(short8v*)(th + (size_t)slot * 8) = h8;
  *(short8v*)(tl + (size_t)slot * 8) = l8;
}

__device__ __forceinline__ void conv_tile_blk(const float* w, unsigned short* th,
                                              unsigned short* tl, int b) {
  int slot = b * 256 + threadIdx.x;   // 320 slots
  if (slot >= 320) return;
  int oc = slot & 15;
  int sfq = slot >> 4;
  int s = sfq >> 2, fq = sfq & 3;
  short8v h8, l8;
#pragma unroll
  for (int j = 0; j < 8; ++j) {
    int k = s * 32 + fq * 8 + j;
    float v = 0.f;
    if (k < 144) {
      int dydx = k >> 4, ic = k & 15;
      v = w[oc * 144 + ic * 9 + dydx];
    }
    short hh, ll; split2(v, hh, ll);
    h8[j] = hh; l8[j] = ll;
  }
  *(short8v*)(th + (size_t)slot * 8) = h8;
  *(short8v*)(tl + (size_t)slot * 8) = l8;
}

// dtbc fused weight: N=640, K=512. rows 0-511: W'=dt_w@xproj[:16]; 512-575: xproj[16:80]; else 0
__device__ __forceinline__ void wdtbc_tile_blk(const float* dtw, const float* xpw,
                                               unsigned short* th, unsigned short* tl, int b) {
  int slot = b * 256 + threadIdx.x;   // 40960 slots (160 blocks)
  int col = slot & 127, kg = (slot >> 7) & 3, rest = slot >> 9;
  int s = rest & 15, nt = rest >> 4;  // NS = 16
  int d = nt * 128 + col;
  short8v h8, l8;
  if (d < 512) {
    float wrow[16];
#pragma unroll
    for (int r = 0; r < 16; ++r) wrow[r] = dtw[d * 16 + r];
#pragma unroll
    for (int j = 0; j < 8; ++j) {
      int k = s * 32 + kg * 8 + j;
      float v = 0.f;
#pragma unroll
      for (int r = 0; r < 16; ++r) v = fmaf(wrow[r], xpw[r * 512 + k], v);
      short hh, ll; split2(v, hh, ll);
      h8[j] = hh; l8[j] = ll;
    }
  } else {
#pragma unroll
    for (int j = 0; j < 8; ++j) {
      int k = s * 32 + kg * 8 + j;
      float v = (d < 576) ? xpw[(size_t)(d - 512 + 16) * 512 + k] : 0.f;
      short hh, ll; split2(v, hh, ll);
      h8[j] = hh; l8[j] = ll;
    }
  }
  *(short8v*)(th + (size_t)slot * 8) = h8;
  *(short8v*)(tl + (size_t)slot * 8) = l8;
}

// ---------------- mega weight-tiling kernel ----------------
__global__ __launch_bounds__(256) void tile_all(const float* __restrict__ lin0_w,
                                                unsigned short* __restrict__ wt0h,
                                                unsigned short* __restrict__ wt0l,
                                                unsigned short* __restrict__ wmed,
                                                const float* __restrict__ m_in_w,
                                                const float* __restrict__ lin1_w,
                                                const float* __restrict__ m_out_w,
                                                const float* __restrict__ blk_w,
                                                const float* __restrict__ dec_w,
                                                const float* __restrict__ c2_w,
                                                const float* __restrict__ c3_w,
                                                const float* __restrict__ m_dt_w,
                                                const float* __restrict__ m_xproj_w,
                                                unsigned short* __restrict__ wdth,
                                                unsigned short* __restrict__ wdtl,
                                                unsigned short* __restrict__ w2h,
                                                unsigned short* __restrict__ w2l) {
  __shared__ float ls[32 * 264];
  int b = blockIdx.x;
  int tid = threadIdx.x;
  if (b < 512) {
    int ct = b >> 6, kt = b & 63;
    int c0 = ct << 5, k0 = kt << 8;
    for (int u = tid; u < 2048; u += 256) {
      int col_l = u >> 6, f4i = u & 63;
      int k_l = f4i << 2;
      float4 v = *(const float4*)(lin0_w + (size_t)(c0 + col_l) * KBIG + k0 + k_l);
      float vv[4] = {v.x, v.y, v.z, v.w};
#pragma unroll
      for (int j = 0; j < 4; ++j) {
        int idx = k_l + j;
        ls[col_l * 264 + idx + (idx >> 5)] = vv[j];
      }
    }
    __syncthreads();
    for (int oi = tid; oi < 1024; oi += 256) {
      int col_l = oi & 31, c = oi >> 5;
      short8v h8, l8;
#pragma unroll
      for (int j = 0; j < 8; ++j) {
        float v = ls[col_l * 264 + j * 33 + c];
        short hh, ll; split2(v, hh, ll);
        h8[j] = hh; l8[j] = ll;
      }
      size_t slot = ((size_t)(c * 64 + kt)) * 256 + c0 + col_l;
      *(short8v*)(wt0h + slot * 8) = h8;
      *(short8v*)(wt0l + slot * 8) = l8;
    }
    return;
  }
  b -= 512;
  if (b < 128) { med_tile_blk(m_in_w,  wmed,           wmed + 262144,  256, 32768, b); return; }
  b -= 128;
  if (b < 32)  { med_tile_blk(lin1_w,  wmed + 524288,  wmed + 589824,  256, 8192,  b); return; }
  b -= 32;
  if (b < 64)  { med_tile_blk(dec_w,   wmed + 1048576, wmed + 1179648, 512, 16384, b); return; }
  b -= 64;
  if (b < 2)   { conv_tile_blk(c2_w, wmed + 1310720, wmed + 1313280, b); return; }
  b -= 2;
  if (b < 2)   { conv_tile_blk(c3_w, wmed + 1315840, wmed + 1318400, b); return; }
  b -= 2;
  if (b < 160) { wdtbc_tile_blk(m_dt_w, m_xproj_w, wdth, wdtl, b); return; }
  b -= 160;
  // ---- W2 = blk_w @ m_out_w [256][512], LDS-tiled (64 blocks) ----
  {
    int slot = b * 256 + tid;
    int col = slot & 127, kg = (slot >> 7) & 3, rest = slot >> 9;
    int s = rest & 15, nt = rest >> 4;
    int kb2 = s * 32 + ((b & 1) << 4);
    float acc[8];
#pragma unroll
    for (int j = 0; j < 8; ++j) acc[j] = 0.f;
    float* ows = ls + 4224;
    for (int r0 = 0; r0 < 256; r0 += 32) {
      __syncthreads();
      for (int idx = tid; idx < 4096; idx += 256) {
        int dl = idx >> 5, rr = idx & 31;
        ls[dl * 33 + rr] = blk_w[(size_t)(nt * 128 + dl) * 256 + r0 + rr];
      }
      for (int idx = tid; idx < 512; idx += 256) {
        int rr = idx >> 4, kk = idx & 15;
        ows[rr * 16 + kk] = m_out_w[(size_t)(r0 + rr) * 512 + kb2 + kk];
      }
      __syncthreads();
#pragma unroll 4
      for (int rr = 0; rr < 32; ++rr) {
        float bv = ls[col * 33 + rr];
        const float* op = &ows[rr * 16 + ((kg & 1) << 3)];
#pragma unroll
        for (int j = 0; j < 8; ++j) acc[j] = fmaf(bv, op[j], acc[j]);
      }
    }
    short8v h8, l8;
#pragma unroll
    for (int j = 0; j < 8; ++j) {
      short hh, ll; split2(acc[j], hh, ll);
      h8[j] = hh; l8[j] = ll;
    }
    *(short8v*)(w2h + (size_t)slot * 8) = h8;
    *(short8v*)(w2l + (size_t)slot * 8) = l8;
  }
}

// ---------------- lin0 MFMA GEMM: BM=256, BN=256(full), BK=32, split-K=32 ----------------
__global__ __launch_bounds__(512, 2) void lin0_mfma(const float* __restrict__ x,
                                                    const unsigned short* __restrict__ wh,
                                                    const unsigned short* __restrict__ wl,
                                                    float* __restrict__ wsbase) {
  __shared__ short8v Ad[2][2][1024];
  __shared__ short8v Bd[2][2][1024];
  int bid = blockIdx.x;
  int mt = bid >> 5, z = bid & 31;
  int tid = threadIdx.x;
  int lane = tid & 63, wid = tid >> 6;
  int wm = wid >> 2, wn = wid & 3;
  int fi = lane & 15, fq = lane >> 4;
  int arow = tid >> 1, kh = tid & 1;
  const float* xrow = x + (size_t)mt * 4194304 + (size_t)z * 131072 + (size_t)arow * 512;
  int skg = wid & 3, shl = wid >> 2;
  const unsigned short* wsrc = shl ? wl : wh;
  int aoff[8], boff[4];
#pragma unroll
  for (int mi = 0; mi < 8; ++mi) {
    int row = wm * 128 + mi * 16 + fi;
    aoff[mi] = fq * 256 + (row ^ (fq << 2));
  }
#pragma unroll
  for (int ni = 0; ni < 4; ++ni) boff[ni] = fq * 256 + wn * 64 + ni * 16 + fi;

  f32x4 acc[8][4];
#pragma unroll
  for (int mi = 0; mi < 8; ++mi)
#pragma unroll
    for (int ni = 0; ni < 4; ++ni) acc[mi][ni] = (f32x4)(0.f);

  {
    int slotbase = ((z * 16 + 0) * 4 + skg) * 256;
#pragma unroll
    for (int q = 0; q < 4; ++q)
      glds16(wsrc + (size_t)(slotbase + q * 64 + lane) * 8,
             (void*)&Bd[0][shl][skg * 256 + q * 64]);
    int f0 = kh << 4;
    float vv[16];
#pragma unroll
    for (int j4 = 0; j4 < 4; ++j4) {
      float4 v = *(const float4*)(xrow + f0 + 4 * j4);
      vv[4 * j4] = v.x; vv[4 * j4 + 1] = v.y; vv[4 * j4 + 2] = v.z; vv[4 * j4 + 3] = v.w;
    }
#pragma unroll
    for (int jg = 0; jg < 2; ++jg) {
      short8v h8, l8;
#pragma unroll
      for (int j = 0; j < 8; ++j) { short hh, ll; split2(vv[jg * 8 + j], hh, ll); h8[j] = hh; l8[j] = ll; }
      int kg = (kh << 1) + jg;
      int idx = kg * 256 + (arow ^ (kg << 2));
      Ad[0][0][idx] = h8; Ad[0][1][idx] = l8;
    }
    __syncthreads();
  }

  for (int s = 0; s < 16; ++s) {
    int cb = s & 1, nb = cb ^ 1;
    bool more = s < 15;
    float vv[16];
    if (more) {
      int slotbase = ((z * 16 + s + 1) * 4 + skg) * 256;
#pragma unroll
      for (int q = 0; q < 4; ++q)
        glds16(wsrc + (size_t)(slotbase + q * 64 + lane) * 8,
               (void*)&Bd[nb][shl][skg * 256 + q * 64]);
      int f0 = ((s + 1) << 5) + (kh << 4);
#pragma unroll
      for (int j4 = 0; j4 < 4; ++j4) {
        float4 v = *(const float4*)(xrow + f0 + 4 * j4);
        vv[4 * j4] = v.x; vv[4 * j4 + 1] = v.y; vv[4 * j4 + 2] = v.z; vv[4 * j4 + 3] = v.w;
      }
    }
    short8v fah[8], fal[8];
#pragma unroll
    for (int mi = 0; mi < 8; ++mi) { fah[mi] = Ad[cb][0][aoff[mi]]; fal[mi] = Ad[cb][1][aoff[mi]]; }
#pragma unroll
    for (int ni = 0; ni < 4; ++ni) {
      short8v bh = Bd[cb][0][boff[ni]];
      short8v bl = Bd[cb][1][boff[ni]];
#pragma unroll
      for (int mi = 0; mi < 8; ++mi) { MFMA3(acc[mi][ni], fah[mi], fal[mi], bh, bl); }
    }
    if (more) {
#pragma unroll
      for (int jg = 0; jg < 2; ++jg) {
        short8v h8, l8;
#pragma unroll
        for (int j = 0; j < 8; ++j) { short hh, ll; split2(vv[jg * 8 + j], hh, ll); h8[j] = hh; l8[j] = ll; }
        int kg = (kh << 1) + jg;
        int idx = kg * 256 + (arow ^ (kg << 2));
        Ad[nb][0][idx] = h8; Ad[nb][1][idx] = l8;
      }
    }
    __syncthreads();
  }

  size_t slabbase = (z < 16) ? (F_PART + (size_t)z * 524288) : ((size_t)(z - 16) * 524288);
  float* po = wsbase + slabbase + (size_t)mt * 65536;
#pragma unroll
  for (int mi = 0; mi < 8; ++mi)
#pragma unroll
    for (int ni = 0; ni < 4; ++ni) {
      int mloc = wm * 128 + mi * 16 + fq * 4;
      int n = wn * 64 + ni * 16 + fi;
#pragma unroll
      for (int r = 0; r < 4; ++r)
        po[(size_t)(mloc + r) * 256 + n] = acc[mi][ni][r];
    }
}

// ---------------- medium MFMA GEMM: BM=64, BN=128, BK=32, A+B dbuf ----------------
template <int ACT, int HASBIAS, int SRC2, int DTBC>
__global__ __launch_bounds__(256, 2) void med_mfma(const float* __restrict__ A, int lda,
                                                   const float* __restrict__ A2,
                                                   const unsigned short* __restrict__ wh,
                                                   const unsigned short* __restrict__ wl,
                                                   const float* __restrict__ bias,
                                                   float* __restrict__ out,
                                                   float* __restrict__ bc_out,
                                                   int K, int N) {
  __shared__ short8v Ahs[2][2][256];
  __shared__ short8v Bd[2][2][512];
  int nt = blockIdx.x, mt = blockIdx.y;
  int NS = K >> 5;
  int tid = threadIdx.x;
  int lane = tid & 63, wid = tid >> 6;
  int fi = lane & 15, fq = lane >> 4;
  int arow = tid >> 2, akg = tid & 3;
  int awidx = akg * 64 + (arow ^ (akg << 2));
  int m0 = mt << 6;
  size_t wtbase = (size_t)nt * NS;
  int aoff[4], boff[2];
#pragma unroll
  for (int mi = 0; mi < 4; ++mi) {
    int row = mi * 16 + fi;
    aoff[mi] = fq * 64 + (row ^ (fq << 2));
  }
#pragma unroll
  for (int ni = 0; ni < 2; ++ni) boff[ni] = fq * 128 + wid * 32 + ni * 16 + fi;

  f32x4 acc[4][2];
#pragma unroll
  for (int mi = 0; mi < 4; ++mi)
#pragma unroll
    for (int ni = 0; ni < 2; ++ni) acc[mi][ni] = (f32x4)(0.f);

  {
#pragma unroll
    for (int p = 0; p < 2; ++p) {
      int q = (wid << 1) + p;
      size_t gb = wtbase * 8192 + (size_t)q * 1024 + (size_t)lane * 16;
      glds16((const char*)wh + gb, (char*)&Bd[0][0][0] + q * 1024);
      glds16((const char*)wl + gb, (char*)&Bd[0][1][0] + q * 1024);
    }
    const float* gp = A + (size_t)(m0 + arow) * lda + (akg << 3);
    float4 v0 = *(const float4*)gp, v1 = *(const float4*)(gp + 4);
    float vv[8] = {v0.x, v0.y, v0.z, v0.w, v1.x, v1.y, v1.z, v1.w};
    short8v h8, l8;
#pragma unroll
    for (int j = 0; j < 8; ++j) { short hh, ll; split2(vv[j], hh, ll); h8[j] = hh; l8[j] = ll; }
    Ahs[0][0][awidx] = h8; Ahs[0][1][awidx] = l8;
    __syncthreads();
  }

  for (int s = 0; s < NS; ++s) {
    int cb = s & 1, nb = cb ^ 1;
    bool more = (s + 1) < NS;
    float4 v0, v1;
    if (more) {
#pragma unroll
      for (int p = 0; p < 2; ++p) {
        int q = (wid << 1) + p;
        size_t gb = (wtbase + s + 1) * 8192 + (size_t)q * 1024 + (size_t)lane * 16;
        glds16((const char*)wh + gb, (char*)&Bd[nb][0][0] + q * 1024);
        glds16((const char*)wl + gb, (char*)&Bd[nb][1][0] + q * 1024);
      }
      int sk = (s + 1) << 5;
      const float* gp;
      if (SRC2 && sk >= 256)
        gp = A2 + (size_t)(m0 + arow) * 256 + (sk - 256) + (akg << 3);
      else
        gp = A + (size_t)(m0 + arow) * lda + sk + (akg << 3);
      v0 = *(const float4*)gp; v1 = *(const float4*)(gp + 4);
    }
    short8v fah[4], fal[4];
#pragma unroll
    for (int mi = 0; mi < 4; ++mi) { fah[mi] = Ahs[cb][0][aoff[mi]]; fal[mi] = Ahs[cb][1][aoff[mi]]; }
#pragma unroll
    for (int ni = 0; ni < 2; ++ni) {
      short8v bh = Bd[cb][0][boff[ni]];
      short8v bl = Bd[cb][1][boff[ni]];
#pragma unroll
      for (int mi = 0; mi < 4; ++mi) { MFMA3(acc[mi][ni], fah[mi], fal[mi], bh, bl); }
    }
    if (more) {
      float vv[8] = {v0.x, v0.y, v0.z, v0.w, v1.x, v1.y, v1.z, v1.w};
      short8v h8, l8;
#pragma unroll
      for (int j = 0; j < 8; ++j) { short hh, ll; split2(vv[j], hh, ll); h8[j] = hh; l8[j] = ll; }
      Ahs[nb][0][awidx] = h8; Ahs[nb][1][awidx] = l8;
    }
    __syncthreads();
  }

#pragma unroll
  for (int mi = 0; mi < 4; ++mi)
#pragma unroll
    for (int ni = 0; ni < 2; ++ni) {
      int n = (nt << 7) + wid * 32 + ni * 16 + fi;
#pragma unroll
      for (int r = 0; r < 4; ++r) {
        int m = m0 + mi * 16 + fq * 4 + r;
        float a = acc[mi][ni][r];
        if (DTBC) {
          if (n < 512) out[(size_t)m * 512 + n] = softplusf(a + bias[n]);
          else if (n < 576) bc_out[(size_t)m * 64 + (n - 512)] = a;
        } else {
          float v = a + (HASBIAS ? bias[n] : 0.f);
          if (ACT == 1) v = fmaxf(v, 0.f);
          out[(size_t)m * N + n] = v;
        }
      }
    }
}

// ---------------- sum 32 partials + bias -> relu -> LayerNorm ----------------
__global__ __launch_bounds__(256) void ln32_k(const float* part_a, const float* part_b,
                                              const float* __restrict__ bias,
                                              const float* __restrict__ g,
                                              const float* __restrict__ bb,
                                              float* out) {
  int m = blockIdx.x, t = threadIdx.x;
  float s = bias[t];
  for (int z = 0; z < 16; ++z) s += part_a[((size_t)z * MROWS + m) * 256 + t];
  for (int z = 0; z < 16; ++z) s += part_b[((size_t)z * MROWS + m) * 256 + t];
  float v = fmaxf(s, 0.f);
  float sum = v, sq = v * v;
#pragma unroll
  for (int o = 1; o < 64; o <<= 1) { sum += __shfl_xor(sum, o); sq += __shfl_xor(sq, o); }
  __shared__ float s1[4], s2[4];
  int w = t >> 6;
  if ((t & 63) == 0) { s1[w] = sum; s2[w] = sq; }
  __syncthreads();
  sum = s1[0] + s1[1] + s1[2] + s1[3];
  sq  = s2[0] + s2[1] + s2[2] + s2[3];
  float mu  = sum * (1.f / 256.f);
  float var = sq * (1.f / 256.f) - mu * mu;
  out[(size_t)m * 256 + t] = (v - mu) * rsqrtf(var + 1e-5f) * g[t] + bb[t];
}

// ---------------- 1 partial + bias -> relu -> LN -> skip AND xs=skip+pos ----------------
__global__ __launch_bounds__(256) void ln_pos_k(const float* __restrict__ part,
                                                const float* __restrict__ bias,
                                                const float* __restrict__ g,
                                                const float* __restrict__ bb,
                                                const float* __restrict__ pos,
                                                float* __restrict__ skip,
                                                float* __restrict__ xs) {
  int m = blockIdx.x, t = threadIdx.x;
  float s = bias[t] + part[(size_t)m * 256 + t];
  float v = fmaxf(s, 0.f);
  float sum = v, sq = v * v;
#pragma unroll
  for (int o = 1; o < 64; o <<= 1) { sum += __shfl_xor(sum, o); sq += __shfl_xor(sq, o); }
  __shared__ float s1[4], s2[4];
  int w = t >> 6;
  if ((t & 63) == 0) { s1[w] = sum; s2[w] = sq; }
  __syncthreads();
  sum = s1[0] + s1[1] + s1[2] + s1[3];
  sq  = s2[0] + s2[1] + s2[2] + s2[3];
  float mu  = sum * (1.f / 256.f);
  float var = sq * (1.f / 256.f) - mu * mu;
  float o2 = (v - mu) * rsqrtf(var + 1e-5f) * g[t] + bb[t];
  skip[(size_t)m * 256 + t] = o2;
  xs[(size_t)m * 256 + t] = o2 + pos[(m & 255) * 256 + t];
}

// ---------------- causal depthwise conv1d(k=4) + silu ----------------
__global__ __launch_bounds__(256) void conv1d_silu_k(const float* __restrict__ xz,
                                                     const float* __restrict__ w,
                                                     const float* __restrict__ cb,
                                                     float* __restrict__ xc) {
  int i = blockIdx.x * 256 + threadIdx.x;  // over 2048*512
  int m = i >> 9, d = i & 511;
  int b = m >> 8, l = m & 255;
  float s = cb[d];
#pragma unroll
  for (int j = 0; j < 4; ++j) {
    int ll = l - 3 + j;
    if (ll >= 0) s = fmaf(w[(d << 2) + j], xz[((size_t)((b << 8) + ll) << 10) + d], s);
  }
  xc[(size_t)m * 512 + d] = siluf(s);
}

// ---------------- selective scan (16-step windows, dbuf pbuf -> 1 barrier/window) ----------------
__global__ __launch_bounds__(256, 1) void scan_k(const float* __restrict__ dt,
                                                 const float* __restrict__ u,
                                                 const float* __restrict__ bc,
                                                 const float* __restrict__ Alog,
                                                 const float* __restrict__ Dp,
                                                 const float* __restrict__ xz,
                                                 float* __restrict__ yg) {
  __shared__ float pbuf[2][4][2][16][33];
  int tid  = threadIdx.x;
  int widx = tid >> 6, lane = tid & 63;
  int wid  = (blockIdx.x << 2) + widx;
  int n = lane & 31, ch = lane >> 5;
  int d0 = (wid & 255) << 1;
  int d = d0 + ch;
  int b = wid >> 8;
  size_t base = (size_t)b << 8;
  float Av = -__expf(Alog[(d << 5) + n]);
  float Dv0 = Dp[d0], Dv1 = Dp[d0 + 1];
  float h = 0.f;
  int row = lane & 31;
  int rch = row >> 4, rlp = row & 15;
  int nh  = lane >> 5;
  int drow = d0 + rch;
  float Dsel = rch ? Dv1 : Dv0;

  for (int w0 = 0; w0 < 256; w0 += 16) {
    int wb = (w0 >> 4) & 1;
    float dA[16], dBu[16], Cv[16];
#pragma unroll
    for (int j = 0; j < 16; ++j) {
      size_t r = base + w0 + j;
      float dtv = dt[(r << 9) + d];
      float uv  = u [(r << 9) + d];
      float Bv  = bc[(r << 6) + n];
      Cv[j]     = bc[(r << 6) + 32 + n];
      dA[j]  = __expf(dtv * Av);
      dBu[j] = dtv * Bv * uv;
    }
#pragma unroll
    for (int j = 0; j < 16; ++j) {
      h = fmaf(dA[j], h, dBu[j]);
      pbuf[wb][widx][ch][j][n] = h * Cv[j];
    }
    __syncthreads();
    float s = 0.f;
#pragma unroll
    for (int nn = 0; nn < 16; ++nn) s += pbuf[wb][widx][rch][rlp][(nh << 4) + nn];
    s += __shfl_xor(s, 32);
    if (lane < 32) {
      size_t r = base + w0 + rlp;
      float uv = u[(r << 9) + drow];
      float zv = xz[(r << 10) + 512 + drow];
      yg[(r << 9) + drow] = (s + uv * Dsel) * siluf(zv);
    }
  }
}

// ---------------- MFMA implicit-GEMM 3x3 conv, IC=OC=16 ----------------
// FUSE1: input = 1-ch DEC image; conv1 computed in-kernel into the LDS stage.
// POOL:  epilogue = bias+relu -> 2x2 mean -> 1x1 conv (w4,b4) -> final out.
template <int FUSE1, int POOL>
__global__ __launch_bounds__(256, 2) void conv_mfma(const float* __restrict__ in,
                                                    const unsigned short* __restrict__ wth,
                                                    const unsigned short* __restrict__ wtl,
                                                    const float* __restrict__ bias,
                                                    float* __restrict__ out,
                                                    const float* __restrict__ c1w,
                                                    const float* __restrict__ c1b,
                                                    const float* __restrict__ w4,
                                                    const float* __restrict__ b4) {
  __shared__ __align__(16) char smem[61632];
  unsigned short* inh = (unsigned short*)smem;
  unsigned short* inl = inh + 14688;
  float* decs = (float*)(smem + 58752);   // [20][36] (FUSE1 only)
  int bid = blockIdx.x;
  int txi = bid & 7;
  int tyi = (bid >> 3) & 15;
  int bb  = bid >> 7;
  int x0 = txi << 5, y0 = tyi << 4;
  int tid = threadIdx.x;

  if (FUSE1) {
    // stage DEC halo tile 20x36 (1 channel, halo 2)
    for (int i = tid; i < 720; i += 256) {
      int a = i / 36, c = i - a * 36;
      int gy = y0 + a - 2, gx = x0 + c - 2;
      float v = 0.f;
      if (gy >= 0 && gy < 256 && gx >= 0 && gx < 256)
        v = in[(size_t)bb * 65536 + (gy << 8) + gx];
      decs[i] = v;
    }
    __syncthreads();
    // compute C1 tile 16ch x 18y x 34x (relu(conv3x3(dec))), split-bf16 to stage
    for (int i = tid; i < 9792; i += 256) {
      int ic = i / 612, rem = i - ic * 612;
      int y = rem / 34, xx = rem - y * 34;
      int gy = y0 + y - 1, gx = x0 + xx - 1;
      float v = 0.f;
      if (gy >= 0 && gy < 256 && gx >= 0 && gx < 256) {
        float acc = 0.f;
#pragma unroll
        for (int dy = 0; dy < 3; ++dy)
#pragma unroll
          for (int dx = 0; dx < 3; ++dx)
            acc = fmaf(c1w[ic * 9 + dy * 3 + dx], decs[(y + dy) * 36 + xx + dx], acc);
        v = fmaxf(acc + c1b[ic], 0.f);
      }
      short hh, ll; split2(v, hh, ll);
      int a = (y * 34 + xx) * 24 + ic;
      inh[a] = (unsigned short)hh; inl[a] = (unsigned short)ll;
    }
  } else {
    for (int i = tid; i < 9792; i += 256) {
      int ic = i / 612, rem = i - ic * 612;
      int y = rem / 34, xx = rem - y * 34;
      int gy = y0 + y - 1, gx = x0 + xx - 1;
      float v = 0.f;
      if (gy >= 0 && gy < 256 && gx >= 0 && gx < 256)
        v = in[(((size_t)bb * 16 + ic) << 16) + (gy << 8) + gx];
      short hh, ll; split2(v, hh, ll);
      int a = (y * 34 + xx) * 24 + ic;
      inh[a] = (unsigned short)hh; inl[a] = (unsigned short)ll;
    }
  }
  __syncthreads();

  int lane = tid & 63, w = tid >> 6;
  int fi = lane & 15, fq = lane >> 4;
  int fqh = fq >> 1, ich8 = (fq & 1) << 3;

  int adel[5];
#pragma unroll
  for (int s = 0; s < 5; ++s) {
    int dydx = 2 * s + fqh;
    if (dydx > 8) dydx = 8;
    int dy = dydx / 3, dx = dydx - dy * 3;
    adel[s] = (dy * 34 + dx) * 24;
  }
  int abase[8];
#pragma unroll
  for (int q = 0; q < 8; ++q) {
    int px = ((w * 8 + q) << 4) + fi;
    int y = px >> 5, xx = px & 31;
    abase[q] = (y * 34 + xx) * 24 + ich8;
  }
  short8v bh[5], bl[5];
#pragma unroll
  for (int s = 0; s < 5; ++s) {
    int slot = ((s * 4 + fq) * 16 + fi) * 8;
    bh[s] = *(const short8v*)(wth + slot);
    bl[s] = *(const short8v*)(wtl + slot);
  }

  f32x4 acc[8];
#pragma unroll
  for (int q = 0; q < 8; ++q) acc[q] = (f32x4)(0.f);

#pragma unroll
  for (int s = 0; s < 5; ++s) {
#pragma unroll
    for (int q = 0; q < 8; ++q) {
      short8v ah = *(const short8v*)&inh[abase[q] + adel[s]];
      short8v al = *(const short8v*)&inl[abase[q] + adel[s]];
      MFMA3(acc[q], ah, al, bh[s], bl[s]);
    }
  }
  __syncthreads();

  float* outs = (float*)smem;
#pragma unroll
  for (int q = 0; q < 8; ++q) {
    int pxb = ((w * 8 + q) << 4) + (fq << 2);
#pragma unroll
    for (int r = 0; r < 4; ++r)
      outs[fi * 514 + pxb + r] = acc[q][r];
  }
  __syncthreads();
  if (POOL) {
    // bias+relu -> 2x2 mean -> dot(w4) + b4 -> final [8][128][128]
    if (tid < 128) {
      int py = tid >> 4, pxx = tid & 15;
      float s = b4[0];
#pragma unroll
      for (int ic = 0; ic < 16; ++ic) {
        float vb = bias[ic];
        int base = ic * 514 + (py << 6) + (pxx << 1);   // (2py)*32 + 2pxx
        float v00 = fmaxf(outs[base]      + vb, 0.f);
        float v01 = fmaxf(outs[base + 1]  + vb, 0.f);
        float v10 = fmaxf(outs[base + 32] + vb, 0.f);
        float v11 = fmaxf(outs[base + 33] + vb, 0.f);
        float m4 = 0.25f * (v00 + v01 + v10 + v11);
        s = fmaf(w4[ic], m4, s);
      }
      out[(size_t)bb * 16384 + ((y0 >> 1) + py) * 128 + (x0 >> 1) + pxx] = s;
    }
  } else {
    for (int i = tid; i < 8192; i += 256) {
      int oc = i >> 9, px = i & 511;
      int y = px >> 5, xx = px & 31;
      float v = fmaxf(outs[oc * 514 + px] + bias[oc], 0.f);
      out[(((size_t)bb * 16 + oc) << 16) + ((y0 + y) << 8) + x0 + xx] = v;
    }
  }
}

// ---------------- launcher ----------------
extern "C" void kernel_launch(void* const* d_in, const int* in_sizes, int n_in,
                              void* d_out, int out_size, void* d_ws, size_t ws_size,
                              hipStream_t stream) {
  const float* x        = (const float*)d_in[0];
  const float* lin0_w   = (const float*)d_in[1];
  const float* lin0_b   = (const float*)d_in[2];
  const float* ln0_g    = (const float*)d_in[3];
  const float* ln0_bb   = (const float*)d_in[4];
  const float* lin1_w   = (const float*)d_in[5];
  const float* lin1_b   = (const float*)d_in[6];
  const float* ln1_g    = (const float*)d_in[7];
  const float* ln1_bb   = (const float*)d_in[8];
  const float* pos      = (const float*)d_in[9];
  const float* m_in_w   = (const float*)d_in[10];
  const float* m_conv_w = (const float*)d_in[11];
  const float* m_conv_b = (const float*)d_in[12];
  const float* m_xproj_w= (const float*)d_in[13];
  const float* m_dt_w   = (const float*)d_in[14];
  const float* m_dt_b   = (const float*)d_in[15];
  const float* m_Alog   = (const float*)d_in[16];
  const float* m_D      = (const float*)d_in[17];
  const float* m_out_w  = (const float*)d_in[18];
  const float* blk_w    = (const float*)d_in[19];
  const float* blk_b    = (const float*)d_in[20];
  const float* dec_w    = (const float*)d_in[21];
  const float* dec_b    = (const float*)d_in[22];
  const float* c1_w     = (const float*)d_in[23];
  const float* c1_b     = (const float*)d_in[24];
  const float* c2_w     = (const float*)d_in[25];
  const float* c2_b     = (const float*)d_in[26];
  const float* c3_w     = (const float*)d_in[27];
  const float* c3_b     = (const float*)d_in[28];
  const float* c4_w     = (const float*)d_in[29];
  const float* c4_b     = (const float*)d_in[30];

  float* ws  = (float*)d_ws;
  float* out = (float*)d_out;

  unsigned short* wt0h = (unsigned short*)(ws + F_WT0);
  unsigned short* wt0l = wt0h + 4194304;
  unsigned short* wmed = (unsigned short*)(ws + F_WMED);
  unsigned short* inw_h = wmed,           * inw_l = wmed + 262144;
  unsigned short* l1_h  = wmed + 524288,  * l1_l  = wmed + 589824;
  unsigned short* dc_h  = wmed + 1048576, * dc_l  = wmed + 1179648;
  unsigned short* wc2h  = wmed + 1310720, * wc2l  = wmed + 1313280;
  unsigned short* wc3h  = wmed + 1315840, * wc3l  = wmed + 1318400;
  unsigned short* wdth  = (unsigned short*)(ws + F_WDT);
  unsigned short* wdtl  = wdth + 327680;
  unsigned short* w2h   = wdtl + 327680;
  unsigned short* w2l   = w2h + 131072;

  // 1. ALL weight tiling in one launch (964 blocks)
  tile_all<<<964, 256, 0, stream>>>(lin0_w, wt0h, wt0l, wmed,
                                    m_in_w, lin1_w, m_out_w, blk_w, dec_w,
                                    c2_w, c3_w, m_dt_w, m_xproj_w,
                                    wdth, wdtl, w2h, w2l);
  // 2. lin0 MFMA GEMM -> 32 partial slabs
  lin0_mfma<<<256, 512, 0, stream>>>(x, wt0h, wt0l, ws);
  // 3. reduce 32 + bias + relu + LN0 -> xt0
  ln32_k<<<MROWS, 256, 0, stream>>>(ws + F_PART, ws, lin0_b, ln0_g, ln0_bb, ws + F_XT0);
  // 4. lin1 -> part (raw)
  med_mfma<0, 0, 0, 0><<<dim3(2, 32), 256, 0, stream>>>(ws + F_XT0, 256, nullptr, l1_h, l1_l,
                                                        nullptr, ws + F_PART, nullptr, 256, 256);
  // 5. bias+relu+LN1 -> skip AND xs = skip+pos
  ln_pos_k<<<MROWS, 256, 0, stream>>>(ws + F_PART, lin1_b, ln1_g, ln1_bb, pos,
                                      ws + F_SKIP, ws + F_XS);
  // 6. xz = xs @ m_in_w^T  [2048,1024]
  med_mfma<0, 0, 0, 0><<<dim3(8, 32), 256, 0, stream>>>(ws + F_XS, 256, nullptr, inw_h, inw_l,
                                                        nullptr, ws + F_XZ, nullptr, 256, 1024);
  // 7. causal dwconv + silu -> xc
  conv1d_silu_k<<<4096, 256, 0, stream>>>(ws + F_XZ, m_conv_w, m_conv_b, ws + F_XC);
  // 8. fused dt+BC
  med_mfma<0, 1, 0, 1><<<dim3(5, 32), 256, 0, stream>>>(ws + F_XC, 512, nullptr, wdth, wdtl,
                                                        m_dt_b, ws + F_DT, ws + F_XDBL, 512, 512);
  // 9. selective scan + silu(z) gating -> yg
  scan_k<<<512, 256, 0, stream>>>(ws + F_DT, ws + F_XC, ws + F_XDBL, m_Alog, m_D,
                                  ws + F_XZ, ws + F_YG);
  // 10. xs2 = yg @ W2^T + blk_b
  med_mfma<0, 1, 0, 0><<<dim3(2, 32), 256, 0, stream>>>(ws + F_YG, 512, nullptr, w2h, w2l,
                                                        blk_b, ws + F_XS2, nullptr, 512, 256);
  // 11. dec = relu([xs2|skip] @ dec_w^T + dec_b)
  med_mfma<1, 1, 1, 0><<<dim3(2, 32), 256, 0, stream>>>(ws + F_XS2, 256, ws + F_SKIP, dc_h, dc_l,
                                                        dec_b, ws + F_DEC, nullptr, 512, 256);
  // 12. conv1+conv2 fused (C1 computed in-kernel from 1-ch DEC) -> C2
  conv_mfma<1, 0><<<1024, 256, 0, stream>>>(ws + F_DEC, wc2h, wc2l, c2_b, ws + F_C2,
                                            c1_w, c1_b, nullptr, nullptr);
  // 13. conv3 + pool + 1x1 fused -> final out
  conv_mfma<0, 1><<<1024, 256, 0, stream>>>(ws + F_C2, wc3h, wc3l, c3_b, out,
                                            nullptr, nullptr, c4_w, c4_b);
}

// Round 13
// 288.914 us; speedup vs baseline: 1.1611x; 1.0540x over previous
//
#include <hip/hip_runtime.h>
#include <hip/hip_bf16.h>
#include <cstddef>
#include <cstdint>

// ---------------- problem constants ----------------
#define MROWS 2048           // B8*L256
#define KBIG  16384          // DIN*CH32

typedef __attribute__((ext_vector_type(8))) short short8v;
typedef __attribute__((ext_vector_type(4))) float f32x4;
typedef unsigned int u32;

// ---------------- ws layout (float offsets) ----------------
static const size_t F_XT0  = 0;          // 2048*256
static const size_t F_SKIP = 524288;     // 2048*256
static const size_t F_XS   = 1048576;    // 2048*256
static const size_t F_XZ   = 1572864;    // 2048*1024
static const size_t F_XC   = 3670016;    // 2048*512
static const size_t F_XDBL = 4718592;    // 2048*64 (BC only)
static const size_t F_DT   = 4882432;    // 2048*512
static const size_t F_YG   = 5931008;    // 2048*512
static const size_t F_XS2  = 7503872;    // 2048*256
static const size_t F_DEC  = 9076736;    // 2048*256 (ends 9601024)
static const size_t F_WMED = 9700000;    // med W tiles + conv W tiles
static const size_t F_WT0  = 10485760;   // lin0 split-bf16 tiles (ends 14680064)
static const size_t F_PART = 14680064;   // lin0 partial slabs 0-15 (ends 23068672)
// lin0 partial slabs 16-31 live at float offset 0 (early chain region, free during lin0).
static const size_t F_WDT  = 23068672;   // dtbc tiles + W2 tiles
static const size_t F_C2   = 0;          // conv2 output (aliases early chain; DEC @9076736 safe)

__device__ __forceinline__ float siluf(float v)     { return v / (1.f + __expf(-v)); }
__device__ __forceinline__ float softplusf(float v) { return v > 20.f ? v : log1pf(__expf(v)); }

__device__ __forceinline__ void split2(float v, short& h, short& l) {
  __hip_bfloat16 hb = __float2bfloat16(v);
  float hf = __bfloat162float(hb);
  __hip_bfloat16 lb = __float2bfloat16(v - hf);
  h = *(short*)&hb; l = *(short*)&lb;
}

__device__ __forceinline__ void glds16(const void* g, void* l) {
  __builtin_amdgcn_global_load_lds((const __attribute__((address_space(1))) u32*)g,
                                   (__attribute__((address_space(3))) u32*)l, 16, 0, 0);
}

#define MFMA3(acc, ah, al, bh, bl)                                            \
  acc = __builtin_amdgcn_mfma_f32_16x16x32_bf16(ah, bh, acc, 0, 0, 0);        \
  acc = __builtin_amdgcn_mfma_f32_16x16x32_bf16(al, bh, acc, 0, 0, 0);        \
  acc = __builtin_amdgcn_mfma_f32_16x16x32_bf16(ah, bl, acc, 0, 0, 0);

// ---------------- device helpers for weight tiling ----------------
__device__ __forceinline__ void med_tile_blk(const float* w, unsigned short* th,
                                             unsigned short* tl, int K, int nslots, int b) {
  int slot = b * 256 + threadIdx.x;
  if (slot >= nslots) return;
  int NS = K >> 5;
  int col = slot & 127, kg = (slot >> 7) & 3, rest = slot >> 9;
  int s = rest % NS, nt = rest / NS;
  const float* src = w + (size_t)(nt * 128 + col) * K + (s << 5) + (kg << 3);
  short8v h8, l8;
#pragma unroll
  for (int j = 0; j < 8; ++j) {
    short hh, ll; split2(src[j], hh, ll);
    h8[j] = hh; l8[j] = ll;
  }
  *(short8v*)(th + (size_t)slot * 8) = h8;
  *(short8v*)(tl + (size_t)slot * 8) = l8;
}

__device__ __forceinline__ void conv_tile_blk(const float* w, unsigned short* th,
                                              unsigned short* tl, int b) {
  int slot = b * 256 + threadIdx.x;   // 320 slots
  if (slot >= 320) return;
  int oc = slot & 15;
  int sfq = slot >> 4;
  int s = sfq >> 2, fq = sfq & 3;
  short8v h8, l8;
#pragma unroll
  for (int j = 0; j < 8; ++j) {
    int k = s * 32 + fq * 8 + j;
    float v = 0.f;
    if (k < 144) {
      int dydx = k >> 4, ic = k & 15;
      v = w[oc * 144 + ic * 9 + dydx];
    }
    short hh, ll; split2(v, hh, ll);
    h8[j] = hh; l8[j] = ll;
  }
  *(short8v*)(th + (size_t)slot * 8) = h8;
  *(short8v*)(tl + (size_t)slot * 8) = l8;
}

// dtbc fused weight: N=640, K=512. rows 0-511: W'=dt_w@xproj[:16]; 512-575: xproj[16:80]; else 0
__device__ __forceinline__ void wdtbc_tile_blk(const float* dtw, const float* xpw,
                                               unsigned short* th, unsigned short* tl, int b) {
  int slot = b * 256 + threadIdx.x;   // 40960 slots (160 blocks)
  int col = slot & 127, kg = (slot >> 7) & 3, rest = slot >> 9;
  int s = rest & 15, nt = rest >> 4;  // NS = 16
  int d = nt * 128 + col;
  short8v h8, l8;
  if (d < 512) {
    float wrow[16];
#pragma unroll
    for (int r = 0; r < 16; ++r) wrow[r] = dtw[d * 16 + r];
#pragma unroll
    for (int j = 0; j < 8; ++j) {
      int k = s * 32 + kg * 8 + j;
      float v = 0.f;
#pragma unroll
      for (int r = 0; r < 16; ++r) v = fmaf(wrow[r], xpw[r * 512 + k], v);
      short hh, ll; split2(v, hh, ll);
      h8[j] = hh; l8[j] = ll;
    }
  } else {
#pragma unroll
    for (int j = 0; j < 8; ++j) {
      int k = s * 32 + kg * 8 + j;
      float v = (d < 576) ? xpw[(size_t)(d - 512 + 16) * 512 + k] : 0.f;
      short hh, ll; split2(v, hh, ll);
      h8[j] = hh; l8[j] = ll;
    }
  }
  *(short8v*)(th + (size_t)slot * 8) = h8;
  *(short8v*)(tl + (size_t)slot * 8) = l8;
}

// ---------------- mega weight-tiling kernel ----------------
__global__ __launch_bounds__(256) void tile_all(const float* __restrict__ lin0_w,
                                                unsigned short* __restrict__ wt0h,
                                                unsigned short* __restrict__ wt0l,
                                                unsigned short* __restrict__ wmed,
                                                const float* __restrict__ m_in_w,
                                                const float* __restrict__ lin1_w,
                                                const float* __restrict__ m_out_w,
                                                const float* __restrict__ blk_w,
                                                const float* __restrict__ dec_w,
                                                const float* __restrict__ c2_w,
                                                const float* __restrict__ c3_w,
                                                const float* __restrict__ m_dt_w,
                                                const float* __restrict__ m_xproj_w,
                                                unsigned short* __restrict__ wdth,
                                                unsigned short* __restrict__ wdtl,
                                                unsigned short* __restrict__ w2h,
                                                unsigned short* __restrict__ w2l) {
  __shared__ float ls[32 * 264];
  int b = blockIdx.x;
  int tid = threadIdx.x;
  if (b < 512) {
    int ct = b >> 6, kt = b & 63;
    int c0 = ct << 5, k0 = kt << 8;
    for (int u = tid; u < 2048; u += 256) {
      int col_l = u >> 6, f4i = u & 63;
      int k_l = f4i << 2;
      float4 v = *(const float4*)(lin0_w + (size_t)(c0 + col_l) * KBIG + k0 + k_l);
      float vv[4] = {v.x, v.y, v.z, v.w};
#pragma unroll
      for (int j = 0; j < 4; ++j) {
        int idx = k_l + j;
        ls[col_l * 264 + idx + (idx >> 5)] = vv[j];
      }
    }
    __syncthreads();
    for (int oi = tid; oi < 1024; oi += 256) {
      int col_l = oi & 31, c = oi >> 5;
      short8v h8, l8;
#pragma unroll
      for (int j = 0; j < 8; ++j) {
        float v = ls[col_l * 264 + j * 33 + c];
        short hh, ll; split2(v, hh, ll);
        h8[j] = hh; l8[j] = ll;
      }
      size_t slot = ((size_t)(c * 64 + kt)) * 256 + c0 + col_l;
      *(short8v*)(wt0h + slot * 8) = h8;
      *(short8v*)(wt0l + slot * 8) = l8;
    }
    return;
  }
  b -= 512;
  if (b < 128) { med_tile_blk(m_in_w,  wmed,           wmed + 262144,  256, 32768, b); return; }
  b -= 128;
  if (b < 32)  { med_tile_blk(lin1_w,  wmed + 524288,  wmed + 589824,  256, 8192,  b); return; }
  b -= 32;
  if (b < 64)  { med_tile_blk(dec_w,   wmed + 1048576, wmed + 1179648, 512, 16384, b); return; }
  b -= 64;
  if (b < 2)   { conv_tile_blk(c2_w, wmed + 1310720, wmed + 1313280, b); return; }
  b -= 2;
  if (b < 2)   { conv_tile_blk(c3_w, wmed + 1315840, wmed + 1318400, b); return; }
  b -= 2;
  if (b < 160) { wdtbc_tile_blk(m_dt_w, m_xproj_w, wdth, wdtl, b); return; }
  b -= 160;
  // ---- W2 = blk_w @ m_out_w [256][512], LDS-tiled (64 blocks) ----
  {
    int slot = b * 256 + tid;
    int col = slot & 127, kg = (slot >> 7) & 3, rest = slot >> 9;
    int s = rest & 15, nt = rest >> 4;
    int kb2 = s * 32 + ((b & 1) << 4);
    float acc[8];
#pragma unroll
    for (int j = 0; j < 8; ++j) acc[j] = 0.f;
    float* ows = ls + 4224;
    for (int r0 = 0; r0 < 256; r0 += 32) {
      __syncthreads();
      for (int idx = tid; idx < 4096; idx += 256) {
        int dl = idx >> 5, rr = idx & 31;
        ls[dl * 33 + rr] = blk_w[(size_t)(nt * 128 + dl) * 256 + r0 + rr];
      }
      for (int idx = tid; idx < 512; idx += 256) {
        int rr = idx >> 4, kk = idx & 15;
        ows[rr * 16 + kk] = m_out_w[(size_t)(r0 + rr) * 512 + kb2 + kk];
      }
      __syncthreads();
#pragma unroll 4
      for (int rr = 0; rr < 32; ++rr) {
        float bv = ls[col * 33 + rr];
        const float* op = &ows[rr * 16 + ((kg & 1) << 3)];
#pragma unroll
        for (int j = 0; j < 8; ++j) acc[j] = fmaf(bv, op[j], acc[j]);
      }
    }
    short8v h8, l8;
#pragma unroll
    for (int j = 0; j < 8; ++j) {
      short hh, ll; split2(acc[j], hh, ll);
      h8[j] = hh; l8[j] = ll;
    }
    *(short8v*)(w2h + (size_t)slot * 8) = h8;
    *(short8v*)(w2l + (size_t)slot * 8) = l8;
  }
}

// ---------------- lin0 MFMA GEMM: BM=256, BN=256(full), BK=32, split-K=32 ----------------
__global__ __launch_bounds__(512, 2) void lin0_mfma(const float* __restrict__ x,
                                                    const unsigned short* __restrict__ wh,
                                                    const unsigned short* __restrict__ wl,
                                                    float* __restrict__ wsbase) {
  __shared__ short8v Ad[2][2][1024];
  __shared__ short8v Bd[2][2][1024];
  int bid = blockIdx.x;
  int mt = bid >> 5, z = bid & 31;
  int tid = threadIdx.x;
  int lane = tid & 63, wid = tid >> 6;
  int wm = wid >> 2, wn = wid & 3;
  int fi = lane & 15, fq = lane >> 4;
  int arow = tid >> 1, kh = tid & 1;
  const float* xrow = x + (size_t)mt * 4194304 + (size_t)z * 131072 + (size_t)arow * 512;
  int skg = wid & 3, shl = wid >> 2;
  const unsigned short* wsrc = shl ? wl : wh;
  int aoff[8], boff[4];
#pragma unroll
  for (int mi = 0; mi < 8; ++mi) {
    int row = wm * 128 + mi * 16 + fi;
    aoff[mi] = fq * 256 + (row ^ (fq << 2));
  }
#pragma unroll
  for (int ni = 0; ni < 4; ++ni) boff[ni] = fq * 256 + wn * 64 + ni * 16 + fi;

  f32x4 acc[8][4];
#pragma unroll
  for (int mi = 0; mi < 8; ++mi)
#pragma unroll
    for (int ni = 0; ni < 4; ++ni) acc[mi][ni] = (f32x4)(0.f);

  {
    int slotbase = ((z * 16 + 0) * 4 + skg) * 256;
#pragma unroll
    for (int q = 0; q < 4; ++q)
      glds16(wsrc + (size_t)(slotbase + q * 64 + lane) * 8,
             (void*)&Bd[0][shl][skg * 256 + q * 64]);
    int f0 = kh << 4;
    float vv[16];
#pragma unroll
    for (int j4 = 0; j4 < 4; ++j4) {
      float4 v = *(const float4*)(xrow + f0 + 4 * j4);
      vv[4 * j4] = v.x; vv[4 * j4 + 1] = v.y; vv[4 * j4 + 2] = v.z; vv[4 * j4 + 3] = v.w;
    }
#pragma unroll
    for (int jg = 0; jg < 2; ++jg) {
      short8v h8, l8;
#pragma unroll
      for (int j = 0; j < 8; ++j) { short hh, ll; split2(vv[jg * 8 + j], hh, ll); h8[j] = hh; l8[j] = ll; }
      int kg = (kh << 1) + jg;
      int idx = kg * 256 + (arow ^ (kg << 2));
      Ad[0][0][idx] = h8; Ad[0][1][idx] = l8;
    }
    __syncthreads();
  }

  for (int s = 0; s < 16; ++s) {
    int cb = s & 1, nb = cb ^ 1;
    bool more = s < 15;
    float vv[16];
    if (more) {
      int slotbase = ((z * 16 + s + 1) * 4 + skg) * 256;
#pragma unroll
      for (int q = 0; q < 4; ++q)
        glds16(wsrc + (size_t)(slotbase + q * 64 + lane) * 8,
               (void*)&Bd[nb][shl][skg * 256 + q * 64]);
      int f0 = ((s + 1) << 5) + (kh << 4);
#pragma unroll
      for (int j4 = 0; j4 < 4; ++j4) {
        float4 v = *(const float4*)(xrow + f0 + 4 * j4);
        vv[4 * j4] = v.x; vv[4 * j4 + 1] = v.y; vv[4 * j4 + 2] = v.z; vv[4 * j4 + 3] = v.w;
      }
    }
    short8v fah[8], fal[8];
#pragma unroll
    for (int mi = 0; mi < 8; ++mi) { fah[mi] = Ad[cb][0][aoff[mi]]; fal[mi] = Ad[cb][1][aoff[mi]]; }
#pragma unroll
    for (int ni = 0; ni < 4; ++ni) {
      short8v bh = Bd[cb][0][boff[ni]];
      short8v bl = Bd[cb][1][boff[ni]];
#pragma unroll
      for (int mi = 0; mi < 8; ++mi) { MFMA3(acc[mi][ni], fah[mi], fal[mi], bh, bl); }
    }
    if (more) {
#pragma unroll
      for (int jg = 0; jg < 2; ++jg) {
        short8v h8, l8;
#pragma unroll
        for (int j = 0; j < 8; ++j) { short hh, ll; split2(vv[jg * 8 + j], hh, ll); h8[j] = hh; l8[j] = ll; }
        int kg = (kh << 1) + jg;
        int idx = kg * 256 + (arow ^ (kg << 2));
        Ad[nb][0][idx] = h8; Ad[nb][1][idx] = l8;
      }
    }
    __syncthreads();
  }

  size_t slabbase = (z < 16) ? (F_PART + (size_t)z * 524288) : ((size_t)(z - 16) * 524288);
  float* po = wsbase + slabbase + (size_t)mt * 65536;
#pragma unroll
  for (int mi = 0; mi < 8; ++mi)
#pragma unroll
    for (int ni = 0; ni < 4; ++ni) {
      int mloc = wm * 128 + mi * 16 + fq * 4;
      int n = wn * 64 + ni * 16 + fi;
#pragma unroll
      for (int r = 0; r < 4; ++r)
        po[(size_t)(mloc + r) * 256 + n] = acc[mi][ni][r];
    }
}

// ---------------- medium MFMA GEMM: BM=64, BN=64, BK=32, A+B dbuf, 4 blocks/CU ----------------
// 4 waves, wave tile 64x16. Weight image layout unchanged (128-col tiles):
// tile index = nt>>1, col offset = (nt&1)*64. Per-output FP order identical to BN=128 version.
template <int ACT, int HASBIAS, int SRC2, int DTBC>
__global__ __launch_bounds__(256, 4) void med_mfma(const float* __restrict__ A, int lda,
                                                   const float* __restrict__ A2,
                                                   const unsigned short* __restrict__ wh,
                                                   const unsigned short* __restrict__ wl,
                                                   const float* __restrict__ bias,
                                                   float* __restrict__ out,
                                                   float* __restrict__ bc_out,
                                                   int K, int N) {
  __shared__ short8v Ahs[2][2][256];   // [buf][h/l][kg*64+row'] = 16KB
  __shared__ short8v Bd[2][2][256];    // [buf][h/l][kg*64+col]  = 16KB
  int nt = blockIdx.x, mt = blockIdx.y;
  int NS = K >> 5;
  int tid = threadIdx.x;
  int lane = tid & 63, wid = tid >> 6;
  int fi = lane & 15, fq = lane >> 4;
  int arow = tid >> 2, akg = tid & 3;
  int awidx = akg * 64 + (arow ^ (akg << 2));
  int m0 = mt << 6;
  size_t wtbase = (size_t)(nt >> 1) * NS;
  int colbase = (nt & 1) << 6;
  int aoff[4];
#pragma unroll
  for (int mi = 0; mi < 4; ++mi) {
    int row = mi * 16 + fi;
    aoff[mi] = fq * 64 + (row ^ (fq << 2));
  }
  int boff = fq * 64 + wid * 16 + fi;

  f32x4 acc[4];
#pragma unroll
  for (int mi = 0; mi < 4; ++mi) acc[mi] = (f32x4)(0.f);

  // prologue: stage step 0 into buf 0 (wave wid stages kg=wid: h then l)
  {
    size_t slotb = (wtbase * 4 + wid) * 128 + colbase;
    glds16(wh + (slotb + lane) * 8, (void*)&Bd[0][0][wid * 64]);
    glds16(wl + (slotb + lane) * 8, (void*)&Bd[0][1][wid * 64]);
    const float* gp = A + (size_t)(m0 + arow) * lda + (akg << 3);
    float4 v0 = *(const float4*)gp, v1 = *(const float4*)(gp + 4);
    float vv[8] = {v0.x, v0.y, v0.z, v0.w, v1.x, v1.y, v1.z, v1.w};
    short8v h8, l8;
#pragma unroll
    for (int j = 0; j < 8; ++j) { short hh, ll; split2(vv[j], hh, ll); h8[j] = hh; l8[j] = ll; }
    Ahs[0][0][awidx] = h8; Ahs[0][1][awidx] = l8;
    __syncthreads();
  }

  for (int s = 0; s < NS; ++s) {
    int cb = s & 1, nb = cb ^ 1;
    bool more = (s + 1) < NS;
    float4 v0, v1;
    if (more) {
      size_t slotb = ((wtbase + s + 1) * 4 + wid) * 128 + colbase;
      glds16(wh + (slotb + lane) * 8, (void*)&Bd[nb][0][wid * 64]);
      glds16(wl + (slotb + lane) * 8, (void*)&Bd[nb][1][wid * 64]);
      int sk = (s + 1) << 5;
      const float* gp;
      if (SRC2 && sk >= 256)
        gp = A2 + (size_t)(m0 + arow) * 256 + (sk - 256) + (akg << 3);
      else
        gp = A + (size_t)(m0 + arow) * lda + sk + (akg << 3);
      v0 = *(const float4*)gp; v1 = *(const float4*)(gp + 4);
    }
    short8v fah[4], fal[4];
#pragma unroll
    for (int mi = 0; mi < 4; ++mi) { fah[mi] = Ahs[cb][0][aoff[mi]]; fal[mi] = Ahs[cb][1][aoff[mi]]; }
    short8v bh = Bd[cb][0][boff];
    short8v bl = Bd[cb][1][boff];
#pragma unroll
    for (int mi = 0; mi < 4; ++mi) { MFMA3(acc[mi], fah[mi], fal[mi], bh, bl); }
    if (more) {
      float vv[8] = {v0.x, v0.y, v0.z, v0.w, v1.x, v1.y, v1.z, v1.w};
      short8v h8, l8;
#pragma unroll
      for (int j = 0; j < 8; ++j) { short hh, ll; split2(vv[j], hh, ll); h8[j] = hh; l8[j] = ll; }
      Ahs[nb][0][awidx] = h8; Ahs[nb][1][awidx] = l8;
    }
    __syncthreads();
  }

  int n = (nt << 6) + wid * 16 + fi;
#pragma unroll
  for (int mi = 0; mi < 4; ++mi) {
#pragma unroll
    for (int r = 0; r < 4; ++r) {
      int m = m0 + mi * 16 + fq * 4 + r;
      float a = acc[mi][r];
      if (DTBC) {
        if (n < 512) out[(size_t)m * 512 + n] = softplusf(a + bias[n]);
        else if (n < 576) bc_out[(size_t)m * 64 + (n - 512)] = a;
      } else {
        float v = a + (HASBIAS ? bias[n] : 0.f);
        if (ACT == 1) v = fmaxf(v, 0.f);
        out[(size_t)m * N + n] = v;
      }
    }
  }
}

// ---------------- sum 32 partials + bias -> relu -> LayerNorm ----------------
__global__ __launch_bounds__(256) void ln32_k(const float* part_a, const float* part_b,
                                              const float* __restrict__ bias,
                                              const float* __restrict__ g,
                                              const float* __restrict__ bb,
                                              float* out) {
  int m = blockIdx.x, t = threadIdx.x;
  float s = bias[t];
  for (int z = 0; z < 16; ++z) s += part_a[((size_t)z * MROWS + m) * 256 + t];
  for (int z = 0; z < 16; ++z) s += part_b[((size_t)z * MROWS + m) * 256 + t];
  float v = fmaxf(s, 0.f);
  float sum = v, sq = v * v;
#pragma unroll
  for (int o = 1; o < 64; o <<= 1) { sum += __shfl_xor(sum, o); sq += __shfl_xor(sq, o); }
  __shared__ float s1[4], s2[4];
  int w = t >> 6;
  if ((t & 63) == 0) { s1[w] = sum; s2[w] = sq; }
  __syncthreads();
  sum = s1[0] + s1[1] + s1[2] + s1[3];
  sq  = s2[0] + s2[1] + s2[2] + s2[3];
  float mu  = sum * (1.f / 256.f);
  float var = sq * (1.f / 256.f) - mu * mu;
  out[(size_t)m * 256 + t] = (v - mu) * rsqrtf(var + 1e-5f) * g[t] + bb[t];
}

// ---------------- 1 partial + bias -> relu -> LN -> skip AND xs=skip+pos ----------------
__global__ __launch_bounds__(256) void ln_pos_k(const float* __restrict__ part,
                                                const float* __restrict__ bias,
                                                const float* __restrict__ g,
                                                const float* __restrict__ bb,
                                                const float* __restrict__ pos,
                                                float* __restrict__ skip,
                                                float* __restrict__ xs) {
  int m = blockIdx.x, t = threadIdx.x;
  float s = bias[t] + part[(size_t)m * 256 + t];
  float v = fmaxf(s, 0.f);
  float sum = v, sq = v * v;
#pragma unroll
  for (int o = 1; o < 64; o <<= 1) { sum += __shfl_xor(sum, o); sq += __shfl_xor(sq, o); }
  __shared__ float s1[4], s2[4];
  int w = t >> 6;
  if ((t & 63) == 0) { s1[w] = sum; s2[w] = sq; }
  __syncthreads();
  sum = s1[0] + s1[1] + s1[2] + s1[3];
  sq  = s2[0] + s2[1] + s2[2] + s2[3];
  float mu  = sum * (1.f / 256.f);
  float var = sq * (1.f / 256.f) - mu * mu;
  float o2 = (v - mu) * rsqrtf(var + 1e-5f) * g[t] + bb[t];
  skip[(size_t)m * 256 + t] = o2;
  xs[(size_t)m * 256 + t] = o2 + pos[(m & 255) * 256 + t];
}

// ---------------- causal depthwise conv1d(k=4) + silu, float4 vectorized ----------------
__global__ __launch_bounds__(256) void conv1d_silu_k(const float* __restrict__ xz,
                                                     const float* __restrict__ w,
                                                     const float* __restrict__ cb,
                                                     float* __restrict__ xc) {
  int i = blockIdx.x * 256 + threadIdx.x;  // 2048*128 units (4 ch each)
  int m = i >> 7, d4 = (i & 127) << 2;
  int b = m >> 8, l = m & 255;
  float4 w0 = *(const float4*)(w + (d4 + 0) * 4);
  float4 w1 = *(const float4*)(w + (d4 + 1) * 4);
  float4 w2 = *(const float4*)(w + (d4 + 2) * 4);
  float4 w3 = *(const float4*)(w + (d4 + 3) * 4);
  float4 s = *(const float4*)(cb + d4);
  const float wj0[4] = {w0.x, w1.x, w2.x, w3.x};
  const float wj1[4] = {w0.y, w1.y, w2.y, w3.y};
  const float wj2[4] = {w0.z, w1.z, w2.z, w3.z};
  const float wj3[4] = {w0.w, w1.w, w2.w, w3.w};
  const float* wj[4] = {wj0, wj1, wj2, wj3};
#pragma unroll
  for (int j = 0; j < 4; ++j) {
    int ll = l - 3 + j;
    if (ll >= 0) {
      float4 xv = *(const float4*)(xz + ((size_t)((b << 8) + ll) << 10) + d4);
      s.x = fmaf(wj[j][0], xv.x, s.x);
      s.y = fmaf(wj[j][1], xv.y, s.y);
      s.z = fmaf(wj[j][2], xv.z, s.z);
      s.w = fmaf(wj[j][3], xv.w, s.w);
    }
  }
  s.x = siluf(s.x); s.y = siluf(s.y); s.z = siluf(s.z); s.w = siluf(s.w);
  *(float4*)(xc + (size_t)m * 512 + d4) = s;
}

// ---------------- selective scan (16-step windows, dbuf pbuf -> 1 barrier/window) ----------------
__global__ __launch_bounds__(256, 1) void scan_k(const float* __restrict__ dt,
                                                 const float* __restrict__ u,
                                                 const float* __restrict__ bc,
                                                 const float* __restrict__ Alog,
                                                 const float* __restrict__ Dp,
                                                 const float* __restrict__ xz,
                                                 float* __restrict__ yg) {
  __shared__ float pbuf[2][4][2][16][33];
  int tid  = threadIdx.x;
  int widx = tid >> 6, lane = tid & 63;
  int wid  = (blockIdx.x << 2) + widx;
  int n = lane & 31, ch = lane >> 5;
  int d0 = (wid & 255) << 1;
  int d = d0 + ch;
  int b = wid >> 8;
  size_t base = (size_t)b << 8;
  float Av = -__expf(Alog[(d << 5) + n]);
  float Dv0 = Dp[d0], Dv1 = Dp[d0 + 1];
  float h = 0.f;
  int row = lane & 31;
  int rch = row >> 4, rlp = row & 15;
  int nh  = lane >> 5;
  int drow = d0 + rch;
  float Dsel = rch ? Dv1 : Dv0;

  for (int w0 = 0; w0 < 256; w0 += 16) {
    int wb = (w0 >> 4) & 1;
    float dA[16], dBu[16], Cv[16];
#pragma unroll
    for (int j = 0; j < 16; ++j) {
      size_t r = base + w0 + j;
      float dtv = dt[(r << 9) + d];
      float uv  = u [(r << 9) + d];
      float Bv  = bc[(r << 6) + n];
      Cv[j]     = bc[(r << 6) + 32 + n];
      dA[j]  = __expf(dtv * Av);
      dBu[j] = dtv * Bv * uv;
    }
#pragma unroll
    for (int j = 0; j < 16; ++j) {
      h = fmaf(dA[j], h, dBu[j]);
      pbuf[wb][widx][ch][j][n] = h * Cv[j];
    }
    __syncthreads();
    float s = 0.f;
#pragma unroll
    for (int nn = 0; nn < 16; ++nn) s += pbuf[wb][widx][rch][rlp][(nh << 4) + nn];
    s += __shfl_xor(s, 32);
    if (lane < 32) {
      size_t r = base + w0 + rlp;
      float uv = u[(r << 9) + drow];
      float zv = xz[(r << 10) + 512 + drow];
      yg[(r << 9) + drow] = (s + uv * Dsel) * siluf(zv);
    }
  }
}

// ---------------- MFMA implicit-GEMM 3x3 conv, IC=OC=16 ----------------
template <int FUSE1, int POOL>
__global__ __launch_bounds__(256, 2) void conv_mfma(const float* __restrict__ in,
                                                    const unsigned short* __restrict__ wth,
                                                    const unsigned short* __restrict__ wtl,
                                                    const float* __restrict__ bias,
                                                    float* __restrict__ out,
                                                    const float* __restrict__ c1w,
                                                    const float* __restrict__ c1b,
                                                    const float* __restrict__ w4,
                                                    const float* __restrict__ b4) {
  __shared__ __align__(16) char smem[61632];
  unsigned short* inh = (unsigned short*)smem;
  unsigned short* inl = inh + 14688;
  float* decs = (float*)(smem + 58752);   // [20][36] (FUSE1 only)
  int bid = blockIdx.x;
  int txi = bid & 7;
  int tyi = (bid >> 3) & 15;
  int bb  = bid >> 7;
  int x0 = txi << 5, y0 = tyi << 4;
  int tid = threadIdx.x;

  if (FUSE1) {
    for (int i = tid; i < 720; i += 256) {
      int a = i / 36, c = i - a * 36;
      int gy = y0 + a - 2, gx = x0 + c - 2;
      float v = 0.f;
      if (gy >= 0 && gy < 256 && gx >= 0 && gx < 256)
        v = in[(size_t)bb * 65536 + (gy << 8) + gx];
      decs[i] = v;
    }
    __syncthreads();
    for (int i = tid; i < 9792; i += 256) {
      int ic = i / 612, rem = i - ic * 612;
      int y = rem / 34, xx = rem - y * 34;
      int gy = y0 + y - 1, gx = x0 + xx - 1;
      float v = 0.f;
      if (gy >= 0 && gy < 256 && gx >= 0 && gx < 256) {
        float acc = 0.f;
#pragma unroll
        for (int dy = 0; dy < 3; ++dy)
#pragma unroll
          for (int dx = 0; dx < 3; ++dx)
            acc = fmaf(c1w[ic * 9 + dy * 3 + dx], decs[(y + dy) * 36 + xx + dx], acc);
        v = fmaxf(acc + c1b[ic], 0.f);
      }
      short hh, ll; split2(v, hh, ll);
      int a = (y * 34 + xx) * 24 + ic;
      inh[a] = (unsigned short)hh; inl[a] = (unsigned short)ll;
    }
  } else {
    for (int i = tid; i < 9792; i += 256) {
      int ic = i / 612, rem = i - ic * 612;
      int y = rem / 34, xx = rem - y * 34;
      int gy = y0 + y - 1, gx = x0 + xx - 1;
      float v = 0.f;
      if (gy >= 0 && gy < 256 && gx >= 0 && gx < 256)
        v = in[(((size_t)bb * 16 + ic) << 16) + (gy << 8) + gx];
      short hh, ll; split2(v, hh, ll);
      int a = (y * 34 + xx) * 24 + ic;
      inh[a] = (unsigned short)hh; inl[a] = (unsigned short)ll;
    }
  }
  __syncthreads();

  int lane = tid & 63, w = tid >> 6;
  int fi = lane & 15, fq = lane >> 4;
  int fqh = fq >> 1, ich8 = (fq & 1) << 3;

  int adel[5];
#pragma unroll
  for (int s = 0; s < 5; ++s) {
    int dydx = 2 * s + fqh;
    if (dydx > 8) dydx = 8;
    int dy = dydx / 3, dx = dydx - dy * 3;
    adel[s] = (dy * 34 + dx) * 24;
  }
  int abase[8];
#pragma unroll
  for (int q = 0; q < 8; ++q) {
    int px = ((w * 8 + q) << 4) + fi;
    int y = px >> 5, xx = px & 31;
    abase[q] = (y * 34 + xx) * 24 + ich8;
  }
  short8v bh[5], bl[5];
#pragma unroll
  for (int s = 0; s < 5; ++s) {
    int slot = ((s * 4 + fq) * 16 + fi) * 8;
    bh[s] = *(const short8v*)(wth + slot);
    bl[s] = *(const short8v*)(wtl + slot);
  }

  f32x4 acc[8];
#pragma unroll
  for (int q = 0; q < 8; ++q) acc[q] = (f32x4)(0.f);

#pragma unroll
  for (int s = 0; s < 5; ++s) {
#pragma unroll
    for (int q = 0; q < 8; ++q) {
      short8v ah = *(const short8v*)&inh[abase[q] + adel[s]];
      short8v al = *(const short8v*)&inl[abase[q] + adel[s]];
      MFMA3(acc[q], ah, al, bh[s], bl[s]);
    }
  }
  __syncthreads();

  float* outs = (float*)smem;
#pragma unroll
  for (int q = 0; q < 8; ++q) {
    int pxb = ((w * 8 + q) << 4) + (fq << 2);
#pragma unroll
    for (int r = 0; r < 4; ++r)
      outs[fi * 514 + pxb + r] = acc[q][r];
  }
  __syncthreads();
  if (POOL) {
    if (tid < 128) {
      int py = tid >> 4, pxx = tid & 15;
      float s = b4[0];
#pragma unroll
      for (int ic = 0; ic < 16; ++ic) {
        float vb = bias[ic];
        int base = ic * 514 + (py << 6) + (pxx << 1);
        float v00 = fmaxf(outs[base]      + vb, 0.f);
        float v01 = fmaxf(outs[base + 1]  + vb, 0.f);
        float v10 = fmaxf(outs[base + 32] + vb, 0.f);
        float v11 = fmaxf(outs[base + 33] + vb, 0.f);
        float m4 = 0.25f * (v00 + v01 + v10 + v11);
        s = fmaf(w4[ic], m4, s);
      }
      out[(size_t)bb * 16384 + ((y0 >> 1) + py) * 128 + (x0 >> 1) + pxx] = s;
    }
  } else {
    for (int i = tid; i < 8192; i += 256) {
      int oc = i >> 9, px = i & 511;
      int y = px >> 5, xx = px & 31;
      float v = fmaxf(outs[oc * 514 + px] + bias[oc], 0.f);
      out[(((size_t)bb * 16 + oc) << 16) + ((y0 + y) << 8) + x0 + xx] = v;
    }
  }
}

// ---------------- launcher ----------------
extern "C" void kernel_launch(void* const* d_in, const int* in_sizes, int n_in,
                              void* d_out, int out_size, void* d_ws, size_t ws_size,
                              hipStream_t stream) {
  const float* x        = (const float*)d_in[0];
  const float* lin0_w   = (const float*)d_in[1];
  const float* lin0_b   = (const float*)d_in[2];
  const float* ln0_g    = (const float*)d_in[3];
  const float* ln0_bb   = (const float*)d_in[4];
  const float* lin1_w   = (const float*)d_in[5];
  const float* lin1_b   = (const float*)d_in[6];
  const float* ln1_g    = (const float*)d_in[7];
  const float* ln1_bb   = (const float*)d_in[8];
  const float* pos      = (const float*)d_in[9];
  const float* m_in_w   = (const float*)d_in[10];
  const float* m_conv_w = (const float*)d_in[11];
  const float* m_conv_b = (const float*)d_in[12];
  const float* m_xproj_w= (const float*)d_in[13];
  const float* m_dt_w   = (const float*)d_in[14];
  const float* m_dt_b   = (const float*)d_in[15];
  const float* m_Alog   = (const float*)d_in[16];
  const float* m_D      = (const float*)d_in[17];
  const float* m_out_w  = (const float*)d_in[18];
  const float* blk_w    = (const float*)d_in[19];
  const float* blk_b    = (const float*)d_in[20];
  const float* dec_w    = (const float*)d_in[21];
  const float* dec_b    = (const float*)d_in[22];
  const float* c1_w     = (const float*)d_in[23];
  const float* c1_b     = (const float*)d_in[24];
  const float* c2_w     = (const float*)d_in[25];
  const float* c2_b     = (const float*)d_in[26];
  const float* c3_w     = (const float*)d_in[27];
  const float* c3_b     = (const float*)d_in[28];
  const float* c4_w     = (const float*)d_in[29];
  const float* c4_b     = (const float*)d_in[30];

  float* ws  = (float*)d_ws;
  float* out = (float*)d_out;

  unsigned short* wt0h = (unsigned short*)(ws + F_WT0);
  unsigned short* wt0l = wt0h + 4194304;
  unsigned short* wmed = (unsigned short*)(ws + F_WMED);
  unsigned short* inw_h = wmed,           * inw_l = wmed + 262144;
  unsigned short* l1_h  = wmed + 524288,  * l1_l  = wmed + 589824;
  unsigned short* dc_h  = wmed + 1048576, * dc_l  = wmed + 1179648;
  unsigned short* wc2h  = wmed + 1310720, * wc2l  = wmed + 1313280;
  unsigned short* wc3h  = wmed + 1315840, * wc3l  = wmed + 1318400;
  unsigned short* wdth  = (unsigned short*)(ws + F_WDT);
  unsigned short* wdtl  = wdth + 327680;
  unsigned short* w2h   = wdtl + 327680;
  unsigned short* w2l   = w2h + 131072;

  // 1. ALL weight tiling in one launch (964 blocks)
  tile_all<<<964, 256, 0, stream>>>(lin0_w, wt0h, wt0l, wmed,
                                    m_in_w, lin1_w, m_out_w, blk_w, dec_w,
                                    c2_w, c3_w, m_dt_w, m_xproj_w,
                                    wdth, wdtl, w2h, w2l);
  // 2. lin0 MFMA GEMM -> 32 partial slabs
  lin0_mfma<<<256, 512, 0, stream>>>(x, wt0h, wt0l, ws);
  // 3. reduce 32 + bias + relu + LN0 -> xt0
  ln32_k<<<MROWS, 256, 0, stream>>>(ws + F_PART, ws, lin0_b, ln0_g, ln0_bb, ws + F_XT0);
  // 4. lin1 -> part (raw)  [BN=64 -> 128 blocks]
  med_mfma<0, 0, 0, 0><<<dim3(4, 32), 256, 0, stream>>>(ws + F_XT0, 256, nullptr, l1_h, l1_l,
                                                        nullptr, ws + F_PART, nullptr, 256, 256);
  // 5. bias+relu+LN1 -> skip AND xs = skip+pos
  ln_pos_k<<<MROWS, 256, 0, stream>>>(ws + F_PART, lin1_b, ln1_g, ln1_bb, pos,
                                      ws + F_SKIP, ws + F_XS);
  // 6. xz = xs @ m_in_w^T  [2048,1024]  [512 blocks]
  med_mfma<0, 0, 0, 0><<<dim3(16, 32), 256, 0, stream>>>(ws + F_XS, 256, nullptr, inw_h, inw_l,
                                                         nullptr, ws + F_XZ, nullptr, 256, 1024);
  // 7. causal dwconv + silu -> xc (float4)
  conv1d_silu_k<<<1024, 256, 0, stream>>>(ws + F_XZ, m_conv_w, m_conv_b, ws + F_XC);
  // 8. fused dt+BC  [320 blocks]
  med_mfma<0, 1, 0, 1><<<dim3(10, 32), 256, 0, stream>>>(ws + F_XC, 512, nullptr, wdth, wdtl,
                                                         m_dt_b, ws + F_DT, ws + F_XDBL, 512, 640);
  // 9. selective scan + silu(z) gating -> yg
  scan_k<<<512, 256, 0, stream>>>(ws + F_DT, ws + F_XC, ws + F_XDBL, m_Alog, m_D,
                                  ws + F_XZ, ws + F_YG);
  // 10. xs2 = yg @ W2^T + blk_b  [128 blocks]
  med_mfma<0, 1, 0, 0><<<dim3(4, 32), 256, 0, stream>>>(ws + F_YG, 512, nullptr, w2h, w2l,
                                                        blk_b, ws + F_XS2, nullptr, 512, 256);
  // 11. dec = relu([xs2|skip] @ dec_w^T + dec_b)  [128 blocks]
  med_mfma<1, 1, 1, 0><<<dim3(4, 32), 256, 0, stream>>>(ws + F_XS2, 256, ws + F_SKIP, dc_h, dc_l,
                                                        dec_b, ws + F_DEC, nullptr, 512, 256);
  // 12. conv1+conv2 fused -> C2
  conv_mfma<1, 0><<<1024, 256, 0, stream>>>(ws + F_DEC, wc2h, wc2l, c2_b, ws + F_C2,
                                            c1_w, c1_b, nullptr, nullptr);
  // 13. conv3 + pool + 1x1 fused -> final out
  conv_mfma<0, 1><<<1024, 256, 0, stream>>>(ws + F_C2, wc3h, wc3l, c3_b, out,
                                            nullptr, nullptr, c4_w, c4_b);
}